// Round 1
// baseline (381.089 us; speedup 1.0000x reference)
//
#include <hip/hip_runtime.h>

// ---------- types ----------
typedef __bf16 bf16x8 __attribute__((ext_vector_type(8)));
typedef __bf16 bf16x4 __attribute__((ext_vector_type(4)));
typedef float  f32x4  __attribute__((ext_vector_type(4)));

// async global->LDS, 16B per lane; LDS dest = wave-uniform base + lane*16
__device__ __forceinline__ void cp16(void* lds, const void* g) {
  __builtin_amdgcn_global_load_lds(
      (const __attribute__((address_space(1))) unsigned int*)g,
      (__attribute__((address_space(3))) unsigned int*)lds, 16, 0, 0);
}

// =====================================================================
// Fused small conversions: Wq->Wqb, Wk->Wkvb[0:], Wv->Wkvb[131072:], T->Tbf
// =====================================================================
__global__ __launch_bounds__(256) void cvt_small(const float* __restrict__ Wq,
                                                 const float* __restrict__ Wk,
                                                 const float* __restrict__ Wv,
                                                 const float* __restrict__ T,
                                                 __bf16* __restrict__ Wqb,
                                                 __bf16* __restrict__ Wkvb,
                                                 __bf16* __restrict__ Tbf) {
  const int idx = (blockIdx.x * 256 + threadIdx.x) * 4;
  const float* src;
  __bf16* dst;
  int o;
  if (idx < 131072)      { o = idx;          src = Wq; dst = Wqb; }
  else if (idx < 262144) { o = idx - 131072; src = Wk; dst = Wkvb; }
  else if (idx < 393216) { o = idx - 262144; src = Wv; dst = Wkvb + 131072; }
  else                   { o = idx - 393216; src = T;  dst = Tbf; }
  f32x4 v = *(const f32x4*)(src + o);
  bf16x4 b;
  b[0] = (__bf16)v[0]; b[1] = (__bf16)v[1];
  b[2] = (__bf16)v[2]; b[3] = (__bf16)v[3];
  *(bf16x4*)(dst + o) = b;
}

// =====================================================================
// gemm_kv v2: m97-structure 128x128 tile, BK=32, all-cp16 staging.
//   A = Wkv (stacked [Wk;Wv], 512 rows x 512 k, bf16)  -> C row  = d'
//   B = E   (65536 rows x 512 k, f32 staged raw)       -> C col  = n
//   grid (512+8, 4): bx<512 KV n-tiles, my=blockIdx.y in 0..3 m-tiles;
//   bx>=512 & my==0: small Q GEMM (unchanged m97 path).
// Chunk-XOR swizzle c' = c ^ ((c>>3)&7) on 16B chunks, applied to BOTH
// the cp16 global source (inverse) and the fragment-read address ->
// conflict-free ds_read_b128 on both tiles (rule #21: both-sides).
// =====================================================================
__global__ __launch_bounds__(256) void gemm_kv(const float* __restrict__ E,
                                               const __bf16* __restrict__ Wkv,
                                               const __bf16* __restrict__ Wqb,
                                               const __bf16* __restrict__ Tbf,
                                               __bf16* __restrict__ Kp,
                                               __bf16* __restrict__ Vtile,
                                               __bf16* __restrict__ Qw) {
  __shared__ __align__(16) char smem[24576];   // Wt 8KB | Et(f32) 16KB

  const int tid = threadIdx.x;
  const int lane = tid & 63;
  const int q = lane >> 4, ln = lane & 15;
  const int w = tid >> 6;
  const int yy = blockIdx.y;
  const int bx = blockIdx.x;
  const int wm = w >> 1, wn = w & 1;

  if (bx >= 512) {
    // ---- small Q GEMM (verified path, unchanged) ----
    if (yy != 0) return;
    const int t = bx - 512;                // 0..7
    __bf16* At = (__bf16*)smem;            // 128x32
    __bf16* Bt = (__bf16*)(smem + 8192);   // 128x32
    const int nbase = (t & 3) * 128;
    const int mbase = (t >> 2) * 128;
    f32x4 acc[4][4] = {};
    for (int kt = 0; kt < 16; ++kt) {
      const int k0 = kt * 32;
      __syncthreads();
#pragma unroll
      for (int s = 0; s < 2; ++s) {
        const int cbase = (tid & 192) + s * 256;
        const int c = cbase + lane;
        const int row = c >> 2;
        const int kc = (c & 3) * 8;
        cp16(&At[cbase * 8], Wqb + (size_t)(mbase + row) * 512 + k0 + kc);
        cp16(&Bt[cbase * 8], Tbf + (size_t)(nbase + row) * 512 + k0 + kc);
      }
      __syncthreads();
      bf16x8 af[4], bfr[4];
#pragma unroll
      for (int f = 0; f < 4; ++f) {
        af[f]  = *(const bf16x8*)&At[(wm * 64 + f * 16 + ln) * 32 + q * 8];
        bfr[f] = *(const bf16x8*)&Bt[(wn * 64 + f * 16 + ln) * 32 + q * 8];
      }
#pragma unroll
      for (int fm = 0; fm < 4; ++fm)
#pragma unroll
        for (int fn = 0; fn < 4; ++fn)
          acc[fm][fn] = __builtin_amdgcn_mfma_f32_16x16x32_bf16(
              af[fm], bfr[fn], acc[fm][fn], 0, 0, 0);
    }
#pragma unroll
    for (int fm = 0; fm < 4; ++fm)
#pragma unroll
      for (int fn = 0; fn < 4; ++fn) {
        const int m = mbase + wm * 64 + fm * 16 + q * 4;
        const int n = nbase + wn * 64 + fn * 16 + ln;
        f32x4 v = acc[fm][fn];
        bf16x4 o;
        o[0] = (__bf16)v[0]; o[1] = (__bf16)v[1];
        o[2] = (__bf16)v[2]; o[3] = (__bf16)v[3];
        *(bf16x4*)&Qw[(size_t)n * 256 + m] = o;
      }
    return;
  }

  // ================= KV path: 128(d') x 128(n) tile =================
  const int my = yy;                 // m-tile over stacked 512 d'-rows
  const int n0 = bx * 128;           // global E-row base

  // ---- staging setup: slot s holds logical chunk s ^ ((s>>3)&7) ----
  // Wt: 512 chunks (128 rows x 32 k bf16), 2 cp16/thread
  const __bf16* wsrc[2];
  int wbase[2];
#pragma unroll
  for (int s = 0; s < 2; ++s) {
    const int cb = (tid & 192) + s * 256;      // wave-uniform chunk base
    wbase[s] = cb * 16;
    const int c = cb + lane;
    const int lc = c ^ ((c >> 3) & 7);         // logical chunk
    wsrc[s] = Wkv + (size_t)(my * 128 + (lc >> 2)) * 512 + (lc & 3) * 8;
  }
  // Et: 1024 chunks (128 rows x 32 k f32, raw), 4 cp16/thread
  const float* esrc[4];
  int ebase[4];
#pragma unroll
  for (int s = 0; s < 4; ++s) {
    const int cb = (tid & 192) + s * 256;      // covers 0..960 step 64
    ebase[s] = cb * 16;
    const int c = cb + lane;
    const int lc = c ^ ((c >> 3) & 7);
    esrc[s] = E + (size_t)(n0 + (lc >> 3)) * 512 + (lc & 7) * 4;
  }

  // ---- fragment-read byte offsets (constant across K-loop) ----
  int aoff[4], boff[4];
#pragma unroll
  for (int f = 0; f < 4; ++f) {
    const int ra = wm * 64 + f * 16 + ln;      // A row (d')
    const int ca = ((ra << 2) | q) ^ ((ra >> 1) & 7);
    aoff[f] = ca << 4;
    const int rn = wn * 64 + f * 16 + ln;      // B row (n)
    const int cbk = ((rn << 3) | (q << 1)) ^ (rn & 7);
    boff[f] = cbk << 4;
  }

  f32x4 acc[4][4] = {};
  for (int kt = 0; kt < 16; ++kt) {
    __syncthreads();
#pragma unroll
    for (int s = 0; s < 2; ++s) { cp16(smem + wbase[s], wsrc[s]); wsrc[s] += 32; }
#pragma unroll
    for (int s = 0; s < 4; ++s) { cp16(smem + 8192 + ebase[s], esrc[s]); esrc[s] += 32; }
    __syncthreads();

    bf16x8 af[4], bfr[4];
#pragma unroll
    for (int f = 0; f < 4; ++f) {
      af[f] = *(const bf16x8*)(smem + aoff[f]);
      f32x4 e0 = *(const f32x4*)(smem + 8192 + boff[f]);
      f32x4 e1 = *(const f32x4*)(smem + 8192 + (boff[f] ^ 16));
      bf16x8 t;
      t[0] = (__bf16)e0[0]; t[1] = (__bf16)e0[1];
      t[2] = (__bf16)e0[2]; t[3] = (__bf16)e0[3];
      t[4] = (__bf16)e1[0]; t[5] = (__bf16)e1[1];
      t[6] = (__bf16)e1[2]; t[7] = (__bf16)e1[3];
      bfr[f] = t;
    }
#pragma unroll
    for (int fm = 0; fm < 4; ++fm)
#pragma unroll
      for (int fn = 0; fn < 4; ++fn)
        acc[fm][fn] = __builtin_amdgcn_mfma_f32_16x16x32_bf16(
            af[fm], bfr[fn], acc[fm][fn], 0, 0, 0);
  }

  // ---- epilogue: my<2 -> Kp[n][d], my>=2 -> Vtile[g=bx][d][nl] ----
  if (my < 2) {
#pragma unroll
    for (int fm = 0; fm < 4; ++fm)
#pragma unroll
      for (int fn = 0; fn < 4; ++fn) {
        const int d = my * 128 + wm * 64 + fm * 16 + q * 4;
        const int n = n0 + wn * 64 + fn * 16 + ln;
        f32x4 v = acc[fm][fn];
        bf16x4 o;
        o[0] = (__bf16)v[0]; o[1] = (__bf16)v[1];
        o[2] = (__bf16)v[2]; o[3] = (__bf16)v[3];
        *(bf16x4*)&Kp[(size_t)n * 256 + d] = o;
      }
  } else {
    __bf16* Vp = Vtile + (size_t)bx * 32768;
#pragma unroll
    for (int fm = 0; fm < 4; ++fm)
#pragma unroll
      for (int fn = 0; fn < 4; ++fn) {
        const int nl = wn * 64 + fn * 16 + ln;
        f32x4 v = acc[fm][fn];
#pragma unroll
        for (int r = 0; r < 4; ++r) {
          const int d = (my - 2) * 128 + wm * 64 + fm * 16 + q * 4 + r;
          Vp[d * 128 + nl] = (__bf16)v[r];
        }
      }
  }
}

// =====================================================================
// Attention, whole-tile staged (unchanged)
// =====================================================================
#define QLDS_STRIDE 264
#define PLDS_STRIDE 136
__global__ __launch_bounds__(256) void attn_kernel(
    const __bf16* __restrict__ Qw, const __bf16* __restrict__ Kp,
    const __bf16* __restrict__ Vtile, const float* __restrict__ Pb,
    __bf16* __restrict__ Pws, float* __restrict__ Opart,
    float* __restrict__ rowsum) {
  __shared__ __align__(16) __bf16 Qlds[32 * QLDS_STRIDE];   // 16896 B
  __shared__ __align__(16) __bf16 Kl[8 * 128 * 32];         // 65536 B
  __shared__ __align__(16) __bf16 Vl[4 * 256 * 32];         // 65536 B
  __shared__ __align__(16) __bf16 Plds[32 * PLDS_STRIDE];   //  8704 B

  const int tid = threadIdx.x;
  const int lane = tid & 63;
  const int w = tid >> 6;
  const int q = lane >> 4, ln = lane & 15;
  const int b = blockIdx.y;
  const int cx = blockIdx.x;
  const int n0 = cx * 128;

  // ---- stage K-tile: 4096 chunks, layout [kk][row][jc] ----
  const __bf16* Kpb = Kp + (size_t)(b * 4096 + n0) * 256;
#pragma unroll
  for (int s = 0; s < 16; ++s) {
    const int cbase = (tid & 192) + s * 256;
    const int c = cbase + lane;
    const int kk = c >> 9, row = (c >> 2) & 127, jc = c & 3;
    cp16(&Kl[cbase * 8], Kpb + (size_t)row * 256 + kk * 32 + jc * 8);
  }
  // ---- stage V-plane: 4096 chunks, layout [kk][d][jc] ----
  const __bf16* Vplane = Vtile + (size_t)(b * 32 + cx) * 32768;
#pragma unroll
  for (int s = 0; s < 16; ++s) {
    const int cbase = (tid & 192) + s * 256;
    const int c = cbase + lane;
    const int kk = c >> 10, d = (c >> 2) & 255, jc = c & 3;
    cp16(&Vl[cbase * 8], Vplane + (size_t)d * 128 + kk * 32 + jc * 8);
  }
  // ---- stage Q_b [32 x 256] (reg -> padded LDS) ----
  const __bf16* Qb = Qw + (size_t)b * 32 * 256;
#pragma unroll
  for (int s = 0; s < 4; ++s) {
    const int c = tid + s * 256;
    const int row = c >> 5, col = (c & 31) * 8;
    bf16x8 v = *(const bf16x8*)(Qb + (size_t)c * 8);
    *(bf16x8*)&Qlds[row * QLDS_STRIDE + col] = v;
  }
  __syncthreads();

  // ---- QK^T ----
  f32x4 acc[2][2] = {};
  for (int kk = 0; kk < 8; ++kk) {
    bf16x8 a0 = *(const bf16x8*)&Qlds[(ln) * QLDS_STRIDE + kk * 32 + q * 8];
    bf16x8 a1 = *(const bf16x8*)&Qlds[(16 + ln) * QLDS_STRIDE + kk * 32 + q * 8];
    bf16x8 b0 = *(const bf16x8*)&Kl[kk * 4096 + (w * 32 + ln) * 32 + q * 8];
    bf16x8 b1 = *(const bf16x8*)&Kl[kk * 4096 + (w * 32 + 16 + ln) * 32 + q * 8];
    acc[0][0] = __builtin_amdgcn_mfma_f32_16x16x32_bf16(a0, b0, acc[0][0], 0, 0, 0);
    acc[0][1] = __builtin_amdgcn_mfma_f32_16x16x32_bf16(a0, b1, acc[0][1], 0, 0, 0);
    acc[1][0] = __builtin_amdgcn_mfma_f32_16x16x32_bf16(a1, b0, acc[1][0], 0, 0, 0);
    acc[1][1] = __builtin_amdgcn_mfma_f32_16x16x32_bf16(a1, b1, acc[1][1], 0, 0, 0);
  }

  // ---- P = exp(S/16 + logP) ----
  float lp[2];
#pragma unroll
  for (int fn = 0; fn < 2; ++fn) {
    const int n = n0 + w * 32 + fn * 16 + ln;
    float p = Pb[b * 4096 + n];
    p = fminf(fmaxf(p, 0.1f), 0.9f);
    lp[fn] = __logf(p);
  }
  float rs[2][4] = {};
#pragma unroll
  for (int fm = 0; fm < 2; ++fm) {
#pragma unroll
    for (int fn = 0; fn < 2; ++fn) {
      f32x4 s = acc[fm][fn];
#pragma unroll
      for (int r = 0; r < 4; ++r) {
        const float pv = __expf(s[r] * 0.0625f + lp[fn]);
        const int i = fm * 16 + q * 4 + r;
        const int nn = w * 32 + fn * 16 + ln;
        const __bf16 pbv = (__bf16)pv;
        Pws[(size_t)(b * 32 + i) * 4096 + n0 + nn] = pbv;
        Plds[i * PLDS_STRIDE + nn] = pbv;
        rs[fm][r] += pv;
      }
    }
  }
#pragma unroll
  for (int m = 1; m < 16; m <<= 1)
#pragma unroll
    for (int fm = 0; fm < 2; ++fm)
#pragma unroll
      for (int r = 0; r < 4; ++r)
        rs[fm][r] += __shfl_xor(rs[fm][r], m, 64);
  if (ln == 0) {
#pragma unroll
    for (int fm = 0; fm < 2; ++fm)
#pragma unroll
      for (int r = 0; r < 4; ++r)
        atomicAdd(&rowsum[b * 32 + fm * 16 + q * 4 + r], rs[fm][r]);
  }
  __syncthreads();

  // ---- PV ----
  f32x4 acc2[2][4] = {};
  for (int kk = 0; kk < 4; ++kk) {
    bf16x8 pa0 = *(const bf16x8*)&Plds[(ln) * PLDS_STRIDE + kk * 32 + q * 8];
    bf16x8 pa1 = *(const bf16x8*)&Plds[(16 + ln) * PLDS_STRIDE + kk * 32 + q * 8];
#pragma unroll
    for (int fd = 0; fd < 4; ++fd) {
      bf16x8 vb = *(const bf16x8*)&Vl[kk * 8192 + (w * 64 + fd * 16 + ln) * 32 + q * 8];
      acc2[0][fd] = __builtin_amdgcn_mfma_f32_16x16x32_bf16(pa0, vb, acc2[0][fd], 0, 0, 0);
      acc2[1][fd] = __builtin_amdgcn_mfma_f32_16x16x32_bf16(pa1, vb, acc2[1][fd], 0, 0, 0);
    }
  }
  float* Op = Opart + (size_t)cx * 131072;
#pragma unroll
  for (int fm = 0; fm < 2; ++fm)
#pragma unroll
    for (int fd = 0; fd < 4; ++fd)
#pragma unroll
      for (int r = 0; r < 4; ++r) {
        const int i = fm * 16 + q * 4 + r;
        const int d = w * 64 + fd * 16 + ln;
        Op[(size_t)(b * 32 + i) * 256 + d] = acc2[fm][fd][r];
      }
}

// =====================================================================
// norm_p (unchanged)
// =====================================================================
__global__ __launch_bounds__(256) void norm_p(const __bf16* __restrict__ Pws,
                                              const float* __restrict__ rowsum,
                                              float* __restrict__ Aout) {
  const size_t idx = ((size_t)blockIdx.x * 256 + threadIdx.x) * 4;
  const int row = (int)(idx >> 12);
  const float invs = 1.0f / rowsum[row];
  bf16x4 p = *(const bf16x4*)(Pws + idx);
  f32x4 o;
  o[0] = (float)p[0] * invs; o[1] = (float)p[1] * invs;
  o[2] = (float)p[2] * invs; o[3] = (float)p[3] * invs;
  *(f32x4*)(Aout + idx) = o;
}

// =====================================================================
// final (unchanged)
// =====================================================================
__global__ __launch_bounds__(256) void final_kernel(const float* __restrict__ Opart,
                                                    const float* __restrict__ rowsum,
                                                    const float* __restrict__ Wo,
                                                    float* __restrict__ Fout) {
  __shared__ float fl[256];
  __shared__ float redbuf[4];
  const int row = blockIdx.x;
  const int t = threadIdx.x;
  float s = 0.f;
#pragma unroll
  for (int c = 0; c < 32; ++c)
    s += Opart[(size_t)c * 131072 + (size_t)row * 256 + t];
  fl[t] = s;
  __syncthreads();
  const float invs = 1.0f / rowsum[row];
  float f2[2];
#pragma unroll
  for (int h = 0; h < 2; ++h) {
    const int m = t + h * 256;
    const float* wr = Wo + (size_t)m * 256;
    float dot = 0.f;
    for (int d = 0; d < 256; d += 4) {
      f32x4 wv = *(const f32x4*)(wr + d);
      dot += wv[0] * fl[d] + wv[1] * fl[d + 1] + wv[2] * fl[d + 2] + wv[3] * fl[d + 3];
    }
    f2[h] = dot * invs;
  }
  float ps = f2[0] * f2[0] + f2[1] * f2[1];
#pragma unroll
  for (int m = 1; m < 64; m <<= 1) ps += __shfl_xor(ps, m, 64);
  if ((t & 63) == 0) redbuf[t >> 6] = ps;
  __syncthreads();
  const float tot = redbuf[0] + redbuf[1] + redbuf[2] + redbuf[3];
  const float sc = 1.0f / (sqrtf(tot) + 1e-8f);
  Fout[(size_t)row * 512 + t] = f2[0] * sc;
  Fout[(size_t)row * 512 + t + 256] = f2[1] * sc;
}

// =====================================================================
extern "C" void kernel_launch(void* const* d_in, const int* in_sizes, int n_in,
                              void* d_out, int out_size, void* d_ws, size_t ws_size,
                              hipStream_t stream) {
  const float* E  = (const float*)d_in[0];  // [16,4096,512]
  const float* T  = (const float*)d_in[1];  // [16,32,512]
  const float* Pb = (const float*)d_in[2];  // [16,4096]
  const float* Wq = (const float*)d_in[3];  // [256,512]
  const float* Wk = (const float*)d_in[4];
  const float* Wv = (const float*)d_in[5];
  const float* Wo = (const float*)d_in[6];  // [512,256]

  float* out  = (float*)d_out;
  float* Fout = out;             // [512][512] f32
  float* Aout = out + 262144;    // [512][4096] f32

  char* ws = (char*)d_ws;
  __bf16* Kp    = (__bf16*)ws;                  // [65536][256] bf16  33554432 B
  __bf16* Vtile = (__bf16*)(ws + 33554432);     // [512][256][128]    33554432 B
  __bf16* Pws   = (__bf16*)(ws + 67108864);     // [512][4096] bf16    4194304 B
  float*  Opart = (float*)(ws + 71303168);      // [32][512][256] f32 16777216 B
  __bf16* Tbf   = (__bf16*)(ws + 88080384);     //                      524288 B
  __bf16* Wqb   = (__bf16*)(ws + 88604672);     //                      262144 B
  __bf16* Wkvb  = (__bf16*)(ws + 88866816);     //                      524288 B
  __bf16* Qw    = (__bf16*)(ws + 89391104);     // [512][256] bf16      262144 B
  float*  rowsum = (float*)(ws + 89653248);     // [512] f32 (2048 B)

  hipMemsetAsync(rowsum, 0, 2048, stream);

  cvt_small<<<640, 256, 0, stream>>>(Wq, Wk, Wv, T, Wqb, Wkvb, Tbf);

  // KV: 512 n-tiles x 4 m-tiles (Wk|Wv stacked); Q: bx in [512,520) @ y=0
  gemm_kv<<<dim3(520, 4), 256, 0, stream>>>(E, Wkvb, Wqb, Tbf, Kp, Vtile, Qw);

  attn_kernel<<<dim3(32, 16), 256, 0, stream>>>(Qw, Kp, Vtile, Pb, Pws, Opart, rowsum);
  norm_p<<<2048, 256, 0, stream>>>(Pws, rowsum, Aout);
  final_kernel<<<512, 256, 0, stream>>>(Opart, rowsum, Wo, Fout);
}

// Round 2
// 347.210 us; speedup vs baseline: 1.0976x; 1.0976x over previous
//
#include <hip/hip_runtime.h>

// ---------- types ----------
typedef __bf16 bf16x8 __attribute__((ext_vector_type(8)));
typedef __bf16 bf16x4 __attribute__((ext_vector_type(4)));
typedef float  f32x4  __attribute__((ext_vector_type(4)));

// async global->LDS, 16B per lane; LDS dest = wave-uniform base + lane*16
__device__ __forceinline__ void cp16(void* lds, const void* g) {
  __builtin_amdgcn_global_load_lds(
      (const __attribute__((address_space(1))) unsigned int*)g,
      (__attribute__((address_space(3))) unsigned int*)lds, 16, 0, 0);
}

// =====================================================================
// Fused small conversions: Wq->Wqb, Wk->Wkvb[0:], Wv->Wkvb[131072:], T->Tbf
// =====================================================================
__global__ __launch_bounds__(256) void cvt_small(const float* __restrict__ Wq,
                                                 const float* __restrict__ Wk,
                                                 const float* __restrict__ Wv,
                                                 const float* __restrict__ T,
                                                 __bf16* __restrict__ Wqb,
                                                 __bf16* __restrict__ Wkvb,
                                                 __bf16* __restrict__ Tbf) {
  const int idx = (blockIdx.x * 256 + threadIdx.x) * 4;
  const float* src;
  __bf16* dst;
  int o;
  if (idx < 131072)      { o = idx;          src = Wq; dst = Wqb; }
  else if (idx < 262144) { o = idx - 131072; src = Wk; dst = Wkvb; }
  else if (idx < 393216) { o = idx - 262144; src = Wv; dst = Wkvb + 131072; }
  else                   { o = idx - 393216; src = T;  dst = Tbf; }
  f32x4 v = *(const f32x4*)(src + o);
  bf16x4 b;
  b[0] = (__bf16)v[0]; b[1] = (__bf16)v[1];
  b[2] = (__bf16)v[2]; b[3] = (__bf16)v[3];
  *(bf16x4*)(dst + o) = b;
}

// =====================================================================
// gemm_kv: 256m x 64n tile, K=512, BK=32. acc[8][2] = 64 AGPR.
//   y=0, x<1024 : Kp[n][d]       = E@Wk^T
//   y=1, x<1024 : Vtile[g][d][n] = E@Wv^T
//   y=0, x in [1024,1032): Qw = T@Wq^T (m97 128x128 path)
// v3: minimum-T3 schedule. Double-buffered Wt/Et; each step issues
// stage(t+1) (cp16 W + E global->reg) BEFORE compute(t); cvt+ds_write E
// after the MFMA block (T14 write-late, pinned by sched_barrier(0));
// ONE __syncthreads per step -> prefetch latency hides under compute.
// Addressing recomputed per step (no pointer arrays) to keep VGPR low
// (round-1 lesson: VGPR+AGPR>128 halves waves/SIMD).
// =====================================================================
#define ETS 40   // Et row stride (elems): 80 B -> bank spread
__global__ __launch_bounds__(256) void gemm_kv(const float* __restrict__ E,
                                               const __bf16* __restrict__ Wkv,
                                               const __bf16* __restrict__ Wqb,
                                               const __bf16* __restrict__ Tbf,
                                               __bf16* __restrict__ Kp,
                                               __bf16* __restrict__ Vtile,
                                               __bf16* __restrict__ Qw) {
  __shared__ __align__(16) char smem[43008];
  // KV path: Wt dbuf [2][256][32] bf16 = 32768 B, Et dbuf [2][64][ETS] = 10240 B
  __bf16* Wt = (__bf16*)smem;
  __bf16* Et = (__bf16*)(smem + 32768);

  const int tid = threadIdx.x;
  const int lane = tid & 63;
  const int q = lane >> 4, ln = lane & 15;
  const int w = tid >> 6;
  const int yy = blockIdx.y;
  const int bx = blockIdx.x;

  if (bx >= 1024) {
    // ---- small Q GEMM (2-barrier path, unchanged; 8 blocks, negligible) ----
    if (yy == 1) return;
    const int t = bx - 1024;               // 0..7
    __bf16* At = Wt;                       // 128x32
    __bf16* Bt = Wt + 4096;                // 128x32
    const int nbase = (t & 3) * 128;
    const int mbase = (t >> 2) * 128;
    const int wm = w >> 1, wn = w & 1;
    f32x4 acc[4][4] = {};
    for (int kt = 0; kt < 16; ++kt) {
      const int k0 = kt * 32;
      __syncthreads();
#pragma unroll
      for (int s = 0; s < 2; ++s) {
        const int cbase = (tid & 192) + s * 256;
        const int c = cbase + lane;
        const int row = c >> 2;
        const int kc = (c & 3) * 8;
        cp16(&At[cbase * 8], Wqb + (size_t)(mbase + row) * 512 + k0 + kc);
        cp16(&Bt[cbase * 8], Tbf + (size_t)(nbase + row) * 512 + k0 + kc);
      }
      __syncthreads();
      bf16x8 af[4], bfr[4];
#pragma unroll
      for (int f = 0; f < 4; ++f) {
        af[f]  = *(const bf16x8*)&At[(wm * 64 + f * 16 + ln) * 32 + q * 8];
        bfr[f] = *(const bf16x8*)&Bt[(wn * 64 + f * 16 + ln) * 32 + q * 8];
      }
#pragma unroll
      for (int fm = 0; fm < 4; ++fm)
#pragma unroll
        for (int fn = 0; fn < 4; ++fn)
          acc[fm][fn] = __builtin_amdgcn_mfma_f32_16x16x32_bf16(
              af[fm], bfr[fn], acc[fm][fn], 0, 0, 0);
    }
#pragma unroll
    for (int fm = 0; fm < 4; ++fm)
#pragma unroll
      for (int fn = 0; fn < 4; ++fn) {
        const int m = mbase + wm * 64 + fm * 16 + q * 4;
        const int n = nbase + wn * 64 + fn * 16 + ln;
        f32x4 v = acc[fm][fn];
        bf16x4 o;
        o[0] = (__bf16)v[0]; o[1] = (__bf16)v[1];
        o[2] = (__bf16)v[2]; o[3] = (__bf16)v[3];
        *(bf16x4*)&Qw[(size_t)n * 256 + m] = o;
      }
    return;
  }

  // ---- main KV path: 256m x 64n, prefetch-pipelined ----
  const int wm = w >> 1, wn = w & 1;
  const int nbase = bx * 64;
  const __bf16* Wb = Wkv + yy * 131072;    // 256 rows x 512

  f32x4 acc[8][2] = {};

  // ---- prologue: stage kt=0 into buffer 0 ----
  {
#pragma unroll
    for (int s = 0; s < 4; ++s) {
      const int cbase = (tid & 192) + s * 256;
      const int c = cbase + lane;
      cp16(&Wt[cbase * 8], Wb + (size_t)(c >> 2) * 512 + (c & 3) * 8);
    }
    f32x4 ev[2];
#pragma unroll
    for (int s = 0; s < 2; ++s) {
      const int c = tid + s * 256;
      ev[s] = *(const f32x4*)(E + (size_t)(nbase + (c >> 3)) * 512 + (c & 7) * 4);
    }
#pragma unroll
    for (int s = 0; s < 2; ++s) {
      const int c = tid + s * 256;
      bf16x4 b4;
      b4[0] = (__bf16)ev[s][0]; b4[1] = (__bf16)ev[s][1];
      b4[2] = (__bf16)ev[s][2]; b4[3] = (__bf16)ev[s][3];
      *(bf16x4*)&Et[(c >> 3) * ETS + (c & 7) * 4] = b4;
    }
  }
  __syncthreads();

  for (int kt = 0; kt < 16; ++kt) {
    __bf16* Wc = Wt + (kt & 1) * 8192;          // current (elems)
    __bf16* Ec = Et + (kt & 1) * (64 * ETS);
    __bf16* Wn = Wt + ((kt + 1) & 1) * 8192;    // next
    __bf16* En = Et + ((kt + 1) & 1) * (64 * ETS);
    const int k0n = (kt + 1) * 32;

    // ---- issue stage(t+1): async cp16 for W, global->reg for E ----
    f32x4 ev[2];
    if (kt < 15) {
#pragma unroll
      for (int s = 0; s < 4; ++s) {
        const int cbase = (tid & 192) + s * 256;
        const int c = cbase + lane;
        cp16(&Wn[cbase * 8], Wb + (size_t)(c >> 2) * 512 + k0n + (c & 3) * 8);
      }
#pragma unroll
      for (int s = 0; s < 2; ++s) {
        const int c = tid + s * 256;
        ev[s] = *(const f32x4*)(E + (size_t)(nbase + (c >> 3)) * 512 + k0n + (c & 7) * 4);
      }
    }

    // ---- compute current ----
    bf16x8 bfr[2];
#pragma unroll
    for (int fn = 0; fn < 2; ++fn)
      bfr[fn] = *(const bf16x8*)&Ec[(wn * 32 + fn * 16 + ln) * ETS + q * 8];
#pragma unroll
    for (int fm = 0; fm < 8; ++fm) {
      bf16x8 af = *(const bf16x8*)&Wc[(wm * 128 + fm * 16 + ln) * 32 + q * 8];
#pragma unroll
      for (int fn = 0; fn < 2; ++fn)
        acc[fm][fn] = __builtin_amdgcn_mfma_f32_16x16x32_bf16(
            af, bfr[fn], acc[fm][fn], 0, 0, 0);
    }

    // ---- write-late: E cvt+ds_write after MFMA (T14), order pinned ----
    __builtin_amdgcn_sched_barrier(0);
    if (kt < 15) {
#pragma unroll
      for (int s = 0; s < 2; ++s) {
        const int c = tid + s * 256;
        bf16x4 b4;
        b4[0] = (__bf16)ev[s][0]; b4[1] = (__bf16)ev[s][1];
        b4[2] = (__bf16)ev[s][2]; b4[3] = (__bf16)ev[s][3];
        *(bf16x4*)&En[(c >> 3) * ETS + (c & 7) * 4] = b4;
      }
    }
    __syncthreads();   // drains cp16 (vmcnt) + ds_writes; next step reads other buf
  }

  if (yy == 0) {
    // Kp[n*256 + m]: m = base+q*4+r consecutive -> 8B stores
#pragma unroll
    for (int fm = 0; fm < 8; ++fm)
#pragma unroll
      for (int fn = 0; fn < 2; ++fn) {
        const int m = wm * 128 + fm * 16 + q * 4;
        const int n = nbase + wn * 32 + fn * 16 + ln;
        f32x4 v = acc[fm][fn];
        bf16x4 o;
        o[0] = (__bf16)v[0]; o[1] = (__bf16)v[1];
        o[2] = (__bf16)v[2]; o[3] = (__bf16)v[3];
        *(bf16x4*)&Kp[(size_t)n * 256 + m] = o;
      }
  } else {
    // Vtile[g][d][nl]: g = bx>>1, nl = (bx&1)*64 + local n
    __bf16* Vp = Vtile + (size_t)(bx >> 1) * 32768;
    const int noff = (bx & 1) * 64;
#pragma unroll
    for (int fm = 0; fm < 8; ++fm)
#pragma unroll
      for (int fn = 0; fn < 2; ++fn) {
        const int nl = noff + wn * 32 + fn * 16 + ln;
        f32x4 v = acc[fm][fn];
#pragma unroll
        for (int r = 0; r < 4; ++r) {
          const int d = wm * 128 + fm * 16 + q * 4 + r;
          Vp[d * 128 + nl] = (__bf16)v[r];
        }
      }
  }
}

// =====================================================================
// Attention, whole-tile staged (unchanged)
// =====================================================================
#define QLDS_STRIDE 264
#define PLDS_STRIDE 136
__global__ __launch_bounds__(256) void attn_kernel(
    const __bf16* __restrict__ Qw, const __bf16* __restrict__ Kp,
    const __bf16* __restrict__ Vtile, const float* __restrict__ Pb,
    __bf16* __restrict__ Pws, float* __restrict__ Opart,
    float* __restrict__ rowsum) {
  __shared__ __align__(16) __bf16 Qlds[32 * QLDS_STRIDE];   // 16896 B
  __shared__ __align__(16) __bf16 Kl[8 * 128 * 32];         // 65536 B
  __shared__ __align__(16) __bf16 Vl[4 * 256 * 32];         // 65536 B
  __shared__ __align__(16) __bf16 Plds[32 * PLDS_STRIDE];   //  8704 B

  const int tid = threadIdx.x;
  const int lane = tid & 63;
  const int w = tid >> 6;
  const int q = lane >> 4, ln = lane & 15;
  const int b = blockIdx.y;
  const int cx = blockIdx.x;
  const int n0 = cx * 128;

  // ---- stage K-tile: 4096 chunks, layout [kk][row][jc] ----
  const __bf16* Kpb = Kp + (size_t)(b * 4096 + n0) * 256;
#pragma unroll
  for (int s = 0; s < 16; ++s) {
    const int cbase = (tid & 192) + s * 256;
    const int c = cbase + lane;
    const int kk = c >> 9, row = (c >> 2) & 127, jc = c & 3;
    cp16(&Kl[cbase * 8], Kpb + (size_t)row * 256 + kk * 32 + jc * 8);
  }
  // ---- stage V-plane: 4096 chunks, layout [kk][d][jc] ----
  const __bf16* Vplane = Vtile + (size_t)(b * 32 + cx) * 32768;
#pragma unroll
  for (int s = 0; s < 16; ++s) {
    const int cbase = (tid & 192) + s * 256;
    const int c = cbase + lane;
    const int kk = c >> 10, d = (c >> 2) & 255, jc = c & 3;
    cp16(&Vl[cbase * 8], Vplane + (size_t)d * 128 + kk * 32 + jc * 8);
  }
  // ---- stage Q_b [32 x 256] (reg -> padded LDS) ----
  const __bf16* Qb = Qw + (size_t)b * 32 * 256;
#pragma unroll
  for (int s = 0; s < 4; ++s) {
    const int c = tid + s * 256;
    const int row = c >> 5, col = (c & 31) * 8;
    bf16x8 v = *(const bf16x8*)(Qb + (size_t)c * 8);
    *(bf16x8*)&Qlds[row * QLDS_STRIDE + col] = v;
  }
  __syncthreads();

  // ---- QK^T ----
  f32x4 acc[2][2] = {};
  for (int kk = 0; kk < 8; ++kk) {
    bf16x8 a0 = *(const bf16x8*)&Qlds[(ln) * QLDS_STRIDE + kk * 32 + q * 8];
    bf16x8 a1 = *(const bf16x8*)&Qlds[(16 + ln) * QLDS_STRIDE + kk * 32 + q * 8];
    bf16x8 b0 = *(const bf16x8*)&Kl[kk * 4096 + (w * 32 + ln) * 32 + q * 8];
    bf16x8 b1 = *(const bf16x8*)&Kl[kk * 4096 + (w * 32 + 16 + ln) * 32 + q * 8];
    acc[0][0] = __builtin_amdgcn_mfma_f32_16x16x32_bf16(a0, b0, acc[0][0], 0, 0, 0);
    acc[0][1] = __builtin_amdgcn_mfma_f32_16x16x32_bf16(a0, b1, acc[0][1], 0, 0, 0);
    acc[1][0] = __builtin_amdgcn_mfma_f32_16x16x32_bf16(a1, b0, acc[1][0], 0, 0, 0);
    acc[1][1] = __builtin_amdgcn_mfma_f32_16x16x32_bf16(a1, b1, acc[1][1], 0, 0, 0);
  }

  // ---- P = exp(S/16 + logP) ----
  float lp[2];
#pragma unroll
  for (int fn = 0; fn < 2; ++fn) {
    const int n = n0 + w * 32 + fn * 16 + ln;
    float p = Pb[b * 4096 + n];
    p = fminf(fmaxf(p, 0.1f), 0.9f);
    lp[fn] = __logf(p);
  }
  float rs[2][4] = {};
#pragma unroll
  for (int fm = 0; fm < 2; ++fm) {
#pragma unroll
    for (int fn = 0; fn < 2; ++fn) {
      f32x4 s = acc[fm][fn];
#pragma unroll
      for (int r = 0; r < 4; ++r) {
        const float pv = __expf(s[r] * 0.0625f + lp[fn]);
        const int i = fm * 16 + q * 4 + r;
        const int nn = w * 32 + fn * 16 + ln;
        const __bf16 pbv = (__bf16)pv;
        Pws[(size_t)(b * 32 + i) * 4096 + n0 + nn] = pbv;
        Plds[i * PLDS_STRIDE + nn] = pbv;
        rs[fm][r] += pv;
      }
    }
  }
#pragma unroll
  for (int m = 1; m < 16; m <<= 1)
#pragma unroll
    for (int fm = 0; fm < 2; ++fm)
#pragma unroll
      for (int r = 0; r < 4; ++r)
        rs[fm][r] += __shfl_xor(rs[fm][r], m, 64);
  if (ln == 0) {
#pragma unroll
    for (int fm = 0; fm < 2; ++fm)
#pragma unroll
      for (int r = 0; r < 4; ++r)
        atomicAdd(&rowsum[b * 32 + fm * 16 + q * 4 + r], rs[fm][r]);
  }
  __syncthreads();

  // ---- PV ----
  f32x4 acc2[2][4] = {};
  for (int kk = 0; kk < 4; ++kk) {
    bf16x8 pa0 = *(const bf16x8*)&Plds[(ln) * PLDS_STRIDE + kk * 32 + q * 8];
    bf16x8 pa1 = *(const bf16x8*)&Plds[(16 + ln) * PLDS_STRIDE + kk * 32 + q * 8];
#pragma unroll
    for (int fd = 0; fd < 4; ++fd) {
      bf16x8 vb = *(const bf16x8*)&Vl[kk * 8192 + (w * 64 + fd * 16 + ln) * 32 + q * 8];
      acc2[0][fd] = __builtin_amdgcn_mfma_f32_16x16x32_bf16(pa0, vb, acc2[0][fd], 0, 0, 0);
      acc2[1][fd] = __builtin_amdgcn_mfma_f32_16x16x32_bf16(pa1, vb, acc2[1][fd], 0, 0, 0);
    }
  }
  float* Op = Opart + (size_t)cx * 131072;
#pragma unroll
  for (int fm = 0; fm < 2; ++fm)
#pragma unroll
    for (int fd = 0; fd < 4; ++fd)
#pragma unroll
      for (int r = 0; r < 4; ++r) {
        const int i = fm * 16 + q * 4 + r;
        const int d = w * 64 + fd * 16 + ln;
        Op[(size_t)(b * 32 + i) * 256 + d] = acc2[fm][fd][r];
      }
}

// =====================================================================
// norm_p (unchanged)
// =====================================================================
__global__ __launch_bounds__(256) void norm_p(const __bf16* __restrict__ Pws,
                                              const float* __restrict__ rowsum,
                                              float* __restrict__ Aout) {
  const size_t idx = ((size_t)blockIdx.x * 256 + threadIdx.x) * 4;
  const int row = (int)(idx >> 12);
  const float invs = 1.0f / rowsum[row];
  bf16x4 p = *(const bf16x4*)(Pws + idx);
  f32x4 o;
  o[0] = (float)p[0] * invs; o[1] = (float)p[1] * invs;
  o[2] = (float)p[2] * invs; o[3] = (float)p[3] * invs;
  *(f32x4*)(Aout + idx) = o;
}

// =====================================================================
// final (unchanged)
// =====================================================================
__global__ __launch_bounds__(256) void final_kernel(const float* __restrict__ Opart,
                                                    const float* __restrict__ rowsum,
                                                    const float* __restrict__ Wo,
                                                    float* __restrict__ Fout) {
  __shared__ float fl[256];
  __shared__ float redbuf[4];
  const int row = blockIdx.x;
  const int t = threadIdx.x;
  float s = 0.f;
#pragma unroll
  for (int c = 0; c < 32; ++c)
    s += Opart[(size_t)c * 131072 + (size_t)row * 256 + t];
  fl[t] = s;
  __syncthreads();
  const float invs = 1.0f / rowsum[row];
  float f2[2];
#pragma unroll
  for (int h = 0; h < 2; ++h) {
    const int m = t + h * 256;
    const float* wr = Wo + (size_t)m * 256;
    float dot = 0.f;
    for (int d = 0; d < 256; d += 4) {
      f32x4 wv = *(const f32x4*)(wr + d);
      dot += wv[0] * fl[d] + wv[1] * fl[d + 1] + wv[2] * fl[d + 2] + wv[3] * fl[d + 3];
    }
    f2[h] = dot * invs;
  }
  float ps = f2[0] * f2[0] + f2[1] * f2[1];
#pragma unroll
  for (int m = 1; m < 64; m <<= 1) ps += __shfl_xor(ps, m, 64);
  if ((t & 63) == 0) redbuf[t >> 6] = ps;
  __syncthreads();
  const float tot = redbuf[0] + redbuf[1] + redbuf[2] + redbuf[3];
  const float sc = 1.0f / (sqrtf(tot) + 1e-8f);
  Fout[(size_t)row * 512 + t] = f2[0] * sc;
  Fout[(size_t)row * 512 + t + 256] = f2[1] * sc;
}

// =====================================================================
extern "C" void kernel_launch(void* const* d_in, const int* in_sizes, int n_in,
                              void* d_out, int out_size, void* d_ws, size_t ws_size,
                              hipStream_t stream) {
  const float* E  = (const float*)d_in[0];  // [16,4096,512]
  const float* T  = (const float*)d_in[1];  // [16,32,512]
  const float* Pb = (const float*)d_in[2];  // [16,4096]
  const float* Wq = (const float*)d_in[3];  // [256,512]
  const float* Wk = (const float*)d_in[4];
  const float* Wv = (const float*)d_in[5];
  const float* Wo = (const float*)d_in[6];  // [512,256]

  float* out  = (float*)d_out;
  float* Fout = out;             // [512][512] f32
  float* Aout = out + 262144;    // [512][4096] f32

  char* ws = (char*)d_ws;
  __bf16* Kp    = (__bf16*)ws;                  // [65536][256] bf16  33554432 B
  __bf16* Vtile = (__bf16*)(ws + 33554432);     // [512][256][128]    33554432 B
  __bf16* Pws   = (__bf16*)(ws + 67108864);     // [512][4096] bf16    4194304 B
  float*  Opart = (float*)(ws + 71303168);      // [32][512][256] f32 16777216 B
  __bf16* Tbf   = (__bf16*)(ws + 88080384);     //                      524288 B
  __bf16* Wqb   = (__bf16*)(ws + 88604672);     //                      262144 B
  __bf16* Wkvb  = (__bf16*)(ws + 88866816);     //                      524288 B
  __bf16* Qw    = (__bf16*)(ws + 89391104);     // [512][256] bf16      262144 B
  float*  rowsum = (float*)(ws + 89653248);     // [512] f32 (2048 B)

  hipMemsetAsync(rowsum, 0, 2048, stream);

  cvt_small<<<640, 256, 0, stream>>>(Wq, Wk, Wv, T, Wqb, Wkvb, Tbf);

  // Kp (y=0), Vtile (y=1), Qw (y=0, x>=1024) in one launch
  gemm_kv<<<dim3(1032, 2), 256, 0, stream>>>(E, Wkvb, Wqb, Tbf, Kp, Vtile, Qw);

  attn_kernel<<<dim3(32, 16), 256, 0, stream>>>(Qw, Kp, Vtile, Pb, Pws, Opart, rowsum);
  norm_p<<<2048, 256, 0, stream>>>(Pws, rowsum, Aout);
  final_kernel<<<512, 256, 0, stream>>>(Opart, rowsum, Wo, Fout);
}

// Round 3
// 346.806 us; speedup vs baseline: 1.0989x; 1.0012x over previous
//
#include <hip/hip_runtime.h>

// ---------- types ----------
typedef __bf16 bf16x8 __attribute__((ext_vector_type(8)));
typedef __bf16 bf16x4 __attribute__((ext_vector_type(4)));
typedef float  f32x4  __attribute__((ext_vector_type(4)));

// async global->LDS, 16B per lane; LDS dest = wave-uniform base + lane*16
__device__ __forceinline__ void cp16(void* lds, const void* g) {
  __builtin_amdgcn_global_load_lds(
      (const __attribute__((address_space(1))) unsigned int*)g,
      (__attribute__((address_space(3))) unsigned int*)lds, 16, 0, 0);
}

// =====================================================================
// Fused small conversions: Wq->Wqb, Wk->Wkvb[0:], Wv->Wkvb[131072:], T->Tbf
// =====================================================================
__global__ __launch_bounds__(256) void cvt_small(const float* __restrict__ Wq,
                                                 const float* __restrict__ Wk,
                                                 const float* __restrict__ Wv,
                                                 const float* __restrict__ T,
                                                 __bf16* __restrict__ Wqb,
                                                 __bf16* __restrict__ Wkvb,
                                                 __bf16* __restrict__ Tbf) {
  const int idx = (blockIdx.x * 256 + threadIdx.x) * 4;
  const float* src;
  __bf16* dst;
  int o;
  if (idx < 131072)      { o = idx;          src = Wq; dst = Wqb; }
  else if (idx < 262144) { o = idx - 131072; src = Wk; dst = Wkvb; }
  else if (idx < 393216) { o = idx - 262144; src = Wv; dst = Wkvb + 131072; }
  else                   { o = idx - 393216; src = T;  dst = Tbf; }
  f32x4 v = *(const f32x4*)(src + o);
  bf16x4 b;
  b[0] = (__bf16)v[0]; b[1] = (__bf16)v[1];
  b[2] = (__bf16)v[2]; b[3] = (__bf16)v[3];
  *(bf16x4*)(dst + o) = b;
}

// =====================================================================
// gemm_kv v4: 256m(d') x 128n tile, BK=32, acc[8][4] = 128 AGPR.
//   y=0, x<512 : Kp[n][d]       = E@Wk^T
//   y=1, x<512 : Vtile[g][d][n] = E@Wv^T  (g = bx, full 128-n plane)
//   y=0, x in [512,520): Qw = T@Wq^T (m97 128x128 path, unchanged)
// Rationale (round-2 post-mortem): floor was the per-CU LDS read pipe
// (10 ds_read_b128 per 16 MFMA + 4-8-way conflicts on Wt). n=128 gives
// 12 b128 per 32 MFMA; Wt uses a pair-interleaved XOR chunk swizzle
// (both-sides: permuted cp16 SOURCE, linear LDS, matching read offset)
// -> 2 lanes/bank = conflict-free. 2-barrier classic loop (pipelining
// proved a no-op in rounds 1-2). launch_bounds(256,2): 2 waves/SIMD,
// reg cap 256, acc128+~70 VGPR fits without spill.
// =====================================================================
#define ETS 40   // Et row stride (elems): 80 B -> 8 bank-groups, 2-way free
__global__ __launch_bounds__(256, 2) void gemm_kv(const float* __restrict__ E,
                                                  const __bf16* __restrict__ Wkv,
                                                  const __bf16* __restrict__ Wqb,
                                                  const __bf16* __restrict__ Tbf,
                                                  __bf16* __restrict__ Kp,
                                                  __bf16* __restrict__ Vtile,
                                                  __bf16* __restrict__ Qw) {
  __shared__ __align__(16) char smem[26624];
  __bf16* Wt = (__bf16*)smem;              // 256x32 bf16 = 16384 B (swizzled)
  __bf16* Et = (__bf16*)(smem + 16384);    // 128xETS bf16 = 10240 B

  const int tid = threadIdx.x;
  const int lane = tid & 63;
  const int q = lane >> 4, ln = lane & 15;
  const int w = tid >> 6;
  const int yy = blockIdx.y;
  const int bx = blockIdx.x;
  const int wm = w >> 1, wn = w & 1;

  if (bx >= 512) {
    // ---- small Q GEMM (verified path, unchanged) ----
    if (yy == 1) return;
    const int t = bx - 512;                // 0..7
    __bf16* At = Wt;                       // 128x32
    __bf16* Bt = Wt + 4096;                // 128x32
    const int nbase = (t & 3) * 128;
    const int mbase = (t >> 2) * 128;
    f32x4 acc[4][4] = {};
    for (int kt = 0; kt < 16; ++kt) {
      const int k0 = kt * 32;
      __syncthreads();
#pragma unroll
      for (int s = 0; s < 2; ++s) {
        const int cbase = (tid & 192) + s * 256;
        const int c = cbase + lane;
        const int row = c >> 2;
        const int kc = (c & 3) * 8;
        cp16(&At[cbase * 8], Wqb + (size_t)(mbase + row) * 512 + k0 + kc);
        cp16(&Bt[cbase * 8], Tbf + (size_t)(nbase + row) * 512 + k0 + kc);
      }
      __syncthreads();
      bf16x8 af[4], bfr[4];
#pragma unroll
      for (int f = 0; f < 4; ++f) {
        af[f]  = *(const bf16x8*)&At[(wm * 64 + f * 16 + ln) * 32 + q * 8];
        bfr[f] = *(const bf16x8*)&Bt[(wn * 64 + f * 16 + ln) * 32 + q * 8];
      }
#pragma unroll
      for (int fm = 0; fm < 4; ++fm)
#pragma unroll
        for (int fn = 0; fn < 4; ++fn)
          acc[fm][fn] = __builtin_amdgcn_mfma_f32_16x16x32_bf16(
              af[fm], bfr[fn], acc[fm][fn], 0, 0, 0);
    }
#pragma unroll
    for (int fm = 0; fm < 4; ++fm)
#pragma unroll
      for (int fn = 0; fn < 4; ++fn) {
        const int m = mbase + wm * 64 + fm * 16 + q * 4;
        const int n = nbase + wn * 64 + fn * 16 + ln;
        f32x4 v = acc[fm][fn];
        bf16x4 o;
        o[0] = (__bf16)v[0]; o[1] = (__bf16)v[1];
        o[2] = (__bf16)v[2]; o[3] = (__bf16)v[3];
        *(bf16x4*)&Qw[(size_t)n * 256 + m] = o;
      }
    return;
  }

  // ---- main KV path: 256m x 128n ----
  const int nbase = bx * 128;
  const __bf16* Wb = Wkv + yy * 131072;    // 256 rows x 512

  f32x4 acc[8][4] = {};

  for (int kt = 0; kt < 16; ++kt) {
    const int k0 = kt * 32;
    __syncthreads();
    // ---- W stage: 1024 cp16 chunks, pair-interleaved XOR swizzle ----
    // physical chunk p holds logical (row,kc):
    //   sp = p>>3; slot = (p&7) ^ (sp&7); row = 2*sp + (slot>>2); kc = slot&3
#pragma unroll
    for (int s = 0; s < 4; ++s) {
      const int cbase = (tid & 192) + s * 256;
      const int p = cbase + lane;
      const int sp = p >> 3;
      const int slot = (p & 7) ^ (sp & 7);
      const int row = sp * 2 + (slot >> 2);
      const int kc = slot & 3;
      cp16(&Wt[cbase * 8], Wb + (size_t)row * 512 + k0 + kc * 8);
    }
    // ---- E stage: 128x32 f32 reg-staged -> bf16 padded LDS ----
    f32x4 ev[4];
#pragma unroll
    for (int s = 0; s < 4; ++s) {
      const int c = tid + s * 256;
      ev[s] = *(const f32x4*)(E + (size_t)(nbase + (c >> 3)) * 512 + k0 + (c & 7) * 4);
    }
#pragma unroll
    for (int s = 0; s < 4; ++s) {
      const int c = tid + s * 256;
      bf16x4 b4;
      b4[0] = (__bf16)ev[s][0]; b4[1] = (__bf16)ev[s][1];
      b4[2] = (__bf16)ev[s][2]; b4[3] = (__bf16)ev[s][3];
      *(bf16x4*)&Et[(c >> 3) * ETS + (c & 7) * 4] = b4;
    }
    __syncthreads();

    bf16x8 bfr[4];
#pragma unroll
    for (int fn = 0; fn < 4; ++fn)
      bfr[fn] = *(const bf16x8*)&Et[(wn * 64 + fn * 16 + ln) * ETS + q * 8];
#pragma unroll
    for (int fm = 0; fm < 8; ++fm) {
      const int row = wm * 128 + fm * 16 + ln;
      const int slot = (((row & 1) << 2) | q) ^ ((row >> 1) & 7);
      bf16x8 af = *(const bf16x8*)&Wt[(row >> 1) * 64 + slot * 8];
#pragma unroll
      for (int fn = 0; fn < 4; ++fn)
        acc[fm][fn] = __builtin_amdgcn_mfma_f32_16x16x32_bf16(
            af, bfr[fn], acc[fm][fn], 0, 0, 0);
    }
  }

  if (yy == 0) {
    // Kp[n*256 + m]: m = base+q*4+r consecutive -> 8B stores
#pragma unroll
    for (int fm = 0; fm < 8; ++fm)
#pragma unroll
      for (int fn = 0; fn < 4; ++fn) {
        const int m = wm * 128 + fm * 16 + q * 4;
        const int n = nbase + wn * 64 + fn * 16 + ln;
        f32x4 v = acc[fm][fn];
        bf16x4 o;
        o[0] = (__bf16)v[0]; o[1] = (__bf16)v[1];
        o[2] = (__bf16)v[2]; o[3] = (__bf16)v[3];
        *(bf16x4*)&Kp[(size_t)n * 256 + m] = o;
      }
  } else {
    // Vtile[g][d][nl]: g = bx (one full 128-n plane per block)
    __bf16* Vp = Vtile + (size_t)bx * 32768;
#pragma unroll
    for (int fm = 0; fm < 8; ++fm)
#pragma unroll
      for (int fn = 0; fn < 4; ++fn) {
        const int nl = wn * 64 + fn * 16 + ln;
        f32x4 v = acc[fm][fn];
#pragma unroll
        for (int r = 0; r < 4; ++r) {
          const int d = wm * 128 + fm * 16 + q * 4 + r;
          Vp[d * 128 + nl] = (__bf16)v[r];
        }
      }
  }
}

// =====================================================================
// Attention, whole-tile staged (unchanged)
// =====================================================================
#define QLDS_STRIDE 264
#define PLDS_STRIDE 136
__global__ __launch_bounds__(256) void attn_kernel(
    const __bf16* __restrict__ Qw, const __bf16* __restrict__ Kp,
    const __bf16* __restrict__ Vtile, const float* __restrict__ Pb,
    __bf16* __restrict__ Pws, float* __restrict__ Opart,
    float* __restrict__ rowsum) {
  __shared__ __align__(16) __bf16 Qlds[32 * QLDS_STRIDE];   // 16896 B
  __shared__ __align__(16) __bf16 Kl[8 * 128 * 32];         // 65536 B
  __shared__ __align__(16) __bf16 Vl[4 * 256 * 32];         // 65536 B
  __shared__ __align__(16) __bf16 Plds[32 * PLDS_STRIDE];   //  8704 B

  const int tid = threadIdx.x;
  const int lane = tid & 63;
  const int w = tid >> 6;
  const int q = lane >> 4, ln = lane & 15;
  const int b = blockIdx.y;
  const int cx = blockIdx.x;
  const int n0 = cx * 128;

  // ---- stage K-tile: 4096 chunks, layout [kk][row][jc] ----
  const __bf16* Kpb = Kp + (size_t)(b * 4096 + n0) * 256;
#pragma unroll
  for (int s = 0; s < 16; ++s) {
    const int cbase = (tid & 192) + s * 256;
    const int c = cbase + lane;
    const int kk = c >> 9, row = (c >> 2) & 127, jc = c & 3;
    cp16(&Kl[cbase * 8], Kpb + (size_t)row * 256 + kk * 32 + jc * 8);
  }
  // ---- stage V-plane: 4096 chunks, layout [kk][d][jc] ----
  const __bf16* Vplane = Vtile + (size_t)(b * 32 + cx) * 32768;
#pragma unroll
  for (int s = 0; s < 16; ++s) {
    const int cbase = (tid & 192) + s * 256;
    const int c = cbase + lane;
    const int kk = c >> 10, d = (c >> 2) & 255, jc = c & 3;
    cp16(&Vl[cbase * 8], Vplane + (size_t)d * 128 + kk * 32 + jc * 8);
  }
  // ---- stage Q_b [32 x 256] (reg -> padded LDS) ----
  const __bf16* Qb = Qw + (size_t)b * 32 * 256;
#pragma unroll
  for (int s = 0; s < 4; ++s) {
    const int c = tid + s * 256;
    const int row = c >> 5, col = (c & 31) * 8;
    bf16x8 v = *(const bf16x8*)(Qb + (size_t)c * 8);
    *(bf16x8*)&Qlds[row * QLDS_STRIDE + col] = v;
  }
  __syncthreads();

  // ---- QK^T ----
  f32x4 acc[2][2] = {};
  for (int kk = 0; kk < 8; ++kk) {
    bf16x8 a0 = *(const bf16x8*)&Qlds[(ln) * QLDS_STRIDE + kk * 32 + q * 8];
    bf16x8 a1 = *(const bf16x8*)&Qlds[(16 + ln) * QLDS_STRIDE + kk * 32 + q * 8];
    bf16x8 b0 = *(const bf16x8*)&Kl[kk * 4096 + (w * 32 + ln) * 32 + q * 8];
    bf16x8 b1 = *(const bf16x8*)&Kl[kk * 4096 + (w * 32 + 16 + ln) * 32 + q * 8];
    acc[0][0] = __builtin_amdgcn_mfma_f32_16x16x32_bf16(a0, b0, acc[0][0], 0, 0, 0);
    acc[0][1] = __builtin_amdgcn_mfma_f32_16x16x32_bf16(a0, b1, acc[0][1], 0, 0, 0);
    acc[1][0] = __builtin_amdgcn_mfma_f32_16x16x32_bf16(a1, b0, acc[1][0], 0, 0, 0);
    acc[1][1] = __builtin_amdgcn_mfma_f32_16x16x32_bf16(a1, b1, acc[1][1], 0, 0, 0);
  }

  // ---- P = exp(S/16 + logP) ----
  float lp[2];
#pragma unroll
  for (int fn = 0; fn < 2; ++fn) {
    const int n = n0 + w * 32 + fn * 16 + ln;
    float p = Pb[b * 4096 + n];
    p = fminf(fmaxf(p, 0.1f), 0.9f);
    lp[fn] = __logf(p);
  }
  float rs[2][4] = {};
#pragma unroll
  for (int fm = 0; fm < 2; ++fm) {
#pragma unroll
    for (int fn = 0; fn < 2; ++fn) {
      f32x4 s = acc[fm][fn];
#pragma unroll
      for (int r = 0; r < 4; ++r) {
        const float pv = __expf(s[r] * 0.0625f + lp[fn]);
        const int i = fm * 16 + q * 4 + r;
        const int nn = w * 32 + fn * 16 + ln;
        const __bf16 pbv = (__bf16)pv;
        Pws[(size_t)(b * 32 + i) * 4096 + n0 + nn] = pbv;
        Plds[i * PLDS_STRIDE + nn] = pbv;
        rs[fm][r] += pv;
      }
    }
  }
#pragma unroll
  for (int m = 1; m < 16; m <<= 1)
#pragma unroll
    for (int fm = 0; fm < 2; ++fm)
#pragma unroll
      for (int r = 0; r < 4; ++r)
        rs[fm][r] += __shfl_xor(rs[fm][r], m, 64);
  if (ln == 0) {
#pragma unroll
    for (int fm = 0; fm < 2; ++fm)
#pragma unroll
      for (int r = 0; r < 4; ++r)
        atomicAdd(&rowsum[b * 32 + fm * 16 + q * 4 + r], rs[fm][r]);
  }
  __syncthreads();

  // ---- PV ----
  f32x4 acc2[2][4] = {};
  for (int kk = 0; kk < 4; ++kk) {
    bf16x8 pa0 = *(const bf16x8*)&Plds[(ln) * PLDS_STRIDE + kk * 32 + q * 8];
    bf16x8 pa1 = *(const bf16x8*)&Plds[(16 + ln) * PLDS_STRIDE + kk * 32 + q * 8];
#pragma unroll
    for (int fd = 0; fd < 4; ++fd) {
      bf16x8 vb = *(const bf16x8*)&Vl[kk * 8192 + (w * 64 + fd * 16 + ln) * 32 + q * 8];
      acc2[0][fd] = __builtin_amdgcn_mfma_f32_16x16x32_bf16(pa0, vb, acc2[0][fd], 0, 0, 0);
      acc2[1][fd] = __builtin_amdgcn_mfma_f32_16x16x32_bf16(pa1, vb, acc2[1][fd], 0, 0, 0);
    }
  }
  float* Op = Opart + (size_t)cx * 131072;
#pragma unroll
  for (int fm = 0; fm < 2; ++fm)
#pragma unroll
    for (int fd = 0; fd < 4; ++fd)
#pragma unroll
      for (int r = 0; r < 4; ++r) {
        const int i = fm * 16 + q * 4 + r;
        const int d = w * 64 + fd * 16 + ln;
        Op[(size_t)(b * 32 + i) * 256 + d] = acc2[fm][fd][r];
      }
}

// =====================================================================
// norm_p (unchanged)
// =====================================================================
__global__ __launch_bounds__(256) void norm_p(const __bf16* __restrict__ Pws,
                                              const float* __restrict__ rowsum,
                                              float* __restrict__ Aout) {
  const size_t idx = ((size_t)blockIdx.x * 256 + threadIdx.x) * 4;
  const int row = (int)(idx >> 12);
  const float invs = 1.0f / rowsum[row];
  bf16x4 p = *(const bf16x4*)(Pws + idx);
  f32x4 o;
  o[0] = (float)p[0] * invs; o[1] = (float)p[1] * invs;
  o[2] = (float)p[2] * invs; o[3] = (float)p[3] * invs;
  *(f32x4*)(Aout + idx) = o;
}

// =====================================================================
// final (unchanged)
// =====================================================================
__global__ __launch_bounds__(256) void final_kernel(const float* __restrict__ Opart,
                                                    const float* __restrict__ rowsum,
                                                    const float* __restrict__ Wo,
                                                    float* __restrict__ Fout) {
  __shared__ float fl[256];
  __shared__ float redbuf[4];
  const int row = blockIdx.x;
  const int t = threadIdx.x;
  float s = 0.f;
#pragma unroll
  for (int c = 0; c < 32; ++c)
    s += Opart[(size_t)c * 131072 + (size_t)row * 256 + t];
  fl[t] = s;
  __syncthreads();
  const float invs = 1.0f / rowsum[row];
  float f2[2];
#pragma unroll
  for (int h = 0; h < 2; ++h) {
    const int m = t + h * 256;
    const float* wr = Wo + (size_t)m * 256;
    float dot = 0.f;
    for (int d = 0; d < 256; d += 4) {
      f32x4 wv = *(const f32x4*)(wr + d);
      dot += wv[0] * fl[d] + wv[1] * fl[d + 1] + wv[2] * fl[d + 2] + wv[3] * fl[d + 3];
    }
    f2[h] = dot * invs;
  }
  float ps = f2[0] * f2[0] + f2[1] * f2[1];
#pragma unroll
  for (int m = 1; m < 64; m <<= 1) ps += __shfl_xor(ps, m, 64);
  if ((t & 63) == 0) redbuf[t >> 6] = ps;
  __syncthreads();
  const float tot = redbuf[0] + redbuf[1] + redbuf[2] + redbuf[3];
  const float sc = 1.0f / (sqrtf(tot) + 1e-8f);
  Fout[(size_t)row * 512 + t] = f2[0] * sc;
  Fout[(size_t)row * 512 + t + 256] = f2[1] * sc;
}

// =====================================================================
extern "C" void kernel_launch(void* const* d_in, const int* in_sizes, int n_in,
                              void* d_out, int out_size, void* d_ws, size_t ws_size,
                              hipStream_t stream) {
  const float* E  = (const float*)d_in[0];  // [16,4096,512]
  const float* T  = (const float*)d_in[1];  // [16,32,512]
  const float* Pb = (const float*)d_in[2];  // [16,4096]
  const float* Wq = (const float*)d_in[3];  // [256,512]
  const float* Wk = (const float*)d_in[4];
  const float* Wv = (const float*)d_in[5];
  const float* Wo = (const float*)d_in[6];  // [512,256]

  float* out  = (float*)d_out;
  float* Fout = out;             // [512][512] f32
  float* Aout = out + 262144;    // [512][4096] f32

  char* ws = (char*)d_ws;
  __bf16* Kp    = (__bf16*)ws;                  // [65536][256] bf16  33554432 B
  __bf16* Vtile = (__bf16*)(ws + 33554432);     // [512][256][128]    33554432 B
  __bf16* Pws   = (__bf16*)(ws + 67108864);     // [512][4096] bf16    4194304 B
  float*  Opart = (float*)(ws + 71303168);      // [32][512][256] f32 16777216 B
  __bf16* Tbf   = (__bf16*)(ws + 88080384);     //                      524288 B
  __bf16* Wqb   = (__bf16*)(ws + 88604672);     //                      262144 B
  __bf16* Wkvb  = (__bf16*)(ws + 88866816);     //                      524288 B
  __bf16* Qw    = (__bf16*)(ws + 89391104);     // [512][256] bf16      262144 B
  float*  rowsum = (float*)(ws + 89653248);     // [512] f32 (2048 B)

  hipMemsetAsync(rowsum, 0, 2048, stream);

  cvt_small<<<640, 256, 0, stream>>>(Wq, Wk, Wv, T, Wqb, Wkvb, Tbf);

  // Kp (y=0), Vtile (y=1), Qw (y=0, x>=512) in one launch
  gemm_kv<<<dim3(520, 2), 256, 0, stream>>>(E, Wkvb, Wqb, Tbf, Kp, Vtile, Qw);

  attn_kernel<<<dim3(32, 16), 256, 0, stream>>>(Qw, Kp, Vtile, Pb, Pws, Opart, rowsum);
  norm_p<<<2048, 256, 0, stream>>>(Pws, rowsum, Aout);
  final_kernel<<<512, 256, 0, stream>>>(Opart, rowsum, Wo, Fout);
}

// Round 4
// 343.379 us; speedup vs baseline: 1.1098x; 1.0100x over previous
//
#include <hip/hip_runtime.h>

// ---------- types ----------
typedef __bf16 bf16x8 __attribute__((ext_vector_type(8)));
typedef __bf16 bf16x4 __attribute__((ext_vector_type(4)));
typedef float  f32x4  __attribute__((ext_vector_type(4)));

// async global->LDS, 16B per lane; LDS dest = wave-uniform base + lane*16
__device__ __forceinline__ void cp16(void* lds, const void* g) {
  __builtin_amdgcn_global_load_lds(
      (const __attribute__((address_space(1))) unsigned int*)g,
      (__attribute__((address_space(3))) unsigned int*)lds, 16, 0, 0);
}

#define VMCNT8 asm volatile("s_waitcnt vmcnt(8)" ::: "memory")
#define VMCNT0 asm volatile("s_waitcnt vmcnt(0)" ::: "memory")
#define LGKM0  asm volatile("s_waitcnt lgkmcnt(0)" ::: "memory")
#define BARRAW __builtin_amdgcn_s_barrier

// =====================================================================
// Fused small conversions: Wq->Wqb, Wk->Wkvb[0:], Wv->Wkvb[131072:], T->Tbf
// =====================================================================
__global__ __launch_bounds__(256) void cvt_small(const float* __restrict__ Wq,
                                                 const float* __restrict__ Wk,
                                                 const float* __restrict__ Wv,
                                                 const float* __restrict__ T,
                                                 __bf16* __restrict__ Wqb,
                                                 __bf16* __restrict__ Wkvb,
                                                 __bf16* __restrict__ Tbf) {
  const int idx = (blockIdx.x * 256 + threadIdx.x) * 4;
  const float* src;
  __bf16* dst;
  int o;
  if (idx < 131072)      { o = idx;          src = Wq; dst = Wqb; }
  else if (idx < 262144) { o = idx - 131072; src = Wk; dst = Wkvb; }
  else if (idx < 393216) { o = idx - 262144; src = Wv; dst = Wkvb + 131072; }
  else                   { o = idx - 393216; src = T;  dst = Tbf; }
  f32x4 v = *(const f32x4*)(src + o);
  bf16x4 b;
  b[0] = (__bf16)v[0]; b[1] = (__bf16)v[1];
  b[2] = (__bf16)v[2]; b[3] = (__bf16)v[3];
  *(bf16x4*)(dst + o) = b;
}

// =====================================================================
// gemm_kv v5: 256m x 128n tile, BK=32, acc[8][4]=128 AGPR. Round-3 tile
// + MLP pipeline (round-3 post-mortem: all structures stuck at 2 TB/s
// delivered = Little's-law limit; every step drained vmcnt to 0).
// T3/T4: W triple-buffer cp16, E double reg-set + double LDS (T14),
// issue batch(kt+2) -> compute(kt) -> vmcnt(8) (keep newest batch in
// flight) -> cvt E(kt+1)->LDS -> lgkmcnt(0) -> RAW s_barrier (no vmcnt
// drain!). Per-wave vmcnt(8) BEFORE the barrier makes all waves' step-
// (kt+1) staging complete after the barrier (own-portion rule).
// W swizzle + ETS=40 E padding carried over (conflict-verified r3).
// =====================================================================
#define ETS 40   // Et row stride (elems): 80 B -> 8 bank-groups, 2-way free
__device__ __forceinline__ void stage_W(__bf16* Wdst, const __bf16* Wb,
                                        int k0, int tid, int lane) {
#pragma unroll
  for (int s = 0; s < 4; ++s) {
    const int cbase = (tid & 192) + s * 256;
    const int p = cbase + lane;
    const int sp = p >> 3;
    const int slot = (p & 7) ^ (sp & 7);
    const int row = sp * 2 + (slot >> 2);
    const int kc = slot & 3;
    cp16(&Wdst[cbase * 8], Wb + (size_t)row * 512 + k0 + kc * 8);
  }
}
__device__ __forceinline__ void load_E(f32x4* ev, const float* E,
                                       int nbase, int k0, int tid) {
#pragma unroll
  for (int s = 0; s < 4; ++s) {
    const int c = tid + s * 256;
    ev[s] = *(const f32x4*)(E + (size_t)(nbase + (c >> 3)) * 512 + k0 + (c & 7) * 4);
  }
}
__device__ __forceinline__ void cvt_E(__bf16* Edst, const f32x4* ev, int tid) {
#pragma unroll
  for (int s = 0; s < 4; ++s) {
    const int c = tid + s * 256;
    bf16x4 b4;
    b4[0] = (__bf16)ev[s][0]; b4[1] = (__bf16)ev[s][1];
    b4[2] = (__bf16)ev[s][2]; b4[3] = (__bf16)ev[s][3];
    *(bf16x4*)&Edst[(c >> 3) * ETS + (c & 7) * 4] = b4;
  }
}
__device__ __forceinline__ void compute_step(f32x4 (&acc)[8][4], const __bf16* Wc,
                                             const __bf16* Ec, int wm, int wn,
                                             int q, int ln) {
  bf16x8 bfr[4];
#pragma unroll
  for (int fn = 0; fn < 4; ++fn)
    bfr[fn] = *(const bf16x8*)&Ec[(wn * 64 + fn * 16 + ln) * ETS + q * 8];
#pragma unroll
  for (int fm = 0; fm < 8; ++fm) {
    const int row = wm * 128 + fm * 16 + ln;
    const int slot = (((row & 1) << 2) | q) ^ ((row >> 1) & 7);
    bf16x8 af = *(const bf16x8*)&Wc[(row >> 1) * 64 + slot * 8];
#pragma unroll
    for (int fn = 0; fn < 4; ++fn)
      acc[fm][fn] = __builtin_amdgcn_mfma_f32_16x16x32_bf16(
          af, bfr[fn], acc[fm][fn], 0, 0, 0);
  }
}

__global__ __launch_bounds__(256, 2) void gemm_kv(const float* __restrict__ E,
                                                  const __bf16* __restrict__ Wkv,
                                                  const __bf16* __restrict__ Wqb,
                                                  const __bf16* __restrict__ Tbf,
                                                  __bf16* __restrict__ Kp,
                                                  __bf16* __restrict__ Vtile,
                                                  __bf16* __restrict__ Qw) {
  __shared__ __align__(16) char smem[69632];
  __bf16* Wt = (__bf16*)smem;              // 3 x 256x32 bf16 = 49152 B
  __bf16* Et = (__bf16*)(smem + 49152);    // 2 x 128xETS bf16 = 20480 B

  const int tid = threadIdx.x;
  const int lane = tid & 63;
  const int q = lane >> 4, ln = lane & 15;
  const int w = tid >> 6;
  const int yy = blockIdx.y;
  const int bx = blockIdx.x;
  const int wm = w >> 1, wn = w & 1;

  if (bx >= 512) {
    // ---- small Q GEMM (verified path, unchanged) ----
    if (yy == 1) return;
    const int t = bx - 512;                // 0..7
    __bf16* At = Wt;                       // 128x32
    __bf16* Bt = Wt + 4096;                // 128x32
    const int nbase = (t & 3) * 128;
    const int mbase = (t >> 2) * 128;
    f32x4 acc[4][4] = {};
    for (int kt = 0; kt < 16; ++kt) {
      const int k0 = kt * 32;
      __syncthreads();
#pragma unroll
      for (int s = 0; s < 2; ++s) {
        const int cbase = (tid & 192) + s * 256;
        const int c = cbase + lane;
        const int row = c >> 2;
        const int kc = (c & 3) * 8;
        cp16(&At[cbase * 8], Wqb + (size_t)(mbase + row) * 512 + k0 + kc);
        cp16(&Bt[cbase * 8], Tbf + (size_t)(nbase + row) * 512 + k0 + kc);
      }
      __syncthreads();
      bf16x8 af[4], bfr[4];
#pragma unroll
      for (int f = 0; f < 4; ++f) {
        af[f]  = *(const bf16x8*)&At[(wm * 64 + f * 16 + ln) * 32 + q * 8];
        bfr[f] = *(const bf16x8*)&Bt[(wn * 64 + f * 16 + ln) * 32 + q * 8];
      }
#pragma unroll
      for (int fm = 0; fm < 4; ++fm)
#pragma unroll
        for (int fn = 0; fn < 4; ++fn)
          acc[fm][fn] = __builtin_amdgcn_mfma_f32_16x16x32_bf16(
              af[fm], bfr[fn], acc[fm][fn], 0, 0, 0);
    }
#pragma unroll
    for (int fm = 0; fm < 4; ++fm)
#pragma unroll
      for (int fn = 0; fn < 4; ++fn) {
        const int m = mbase + wm * 64 + fm * 16 + q * 4;
        const int n = nbase + wn * 64 + fn * 16 + ln;
        f32x4 v = acc[fm][fn];
        bf16x4 o;
        o[0] = (__bf16)v[0]; o[1] = (__bf16)v[1];
        o[2] = (__bf16)v[2]; o[3] = (__bf16)v[3];
        *(bf16x4*)&Qw[(size_t)n * 256 + m] = o;
      }
    return;
  }

  // ---- main KV path: 256m x 128n, 2-ahead counted-vmcnt pipeline ----
  const int nbase = bx * 128;
  const __bf16* Wb = Wkv + yy * 131072;    // 256 rows x 512
  __bf16* Et0 = Et;
  __bf16* Et1 = Et + 128 * ETS;

  f32x4 acc[8][4] = {};
  f32x4 evA[4], evB[4];   // evA holds E(even step), evB holds E(odd step)

  // ---- prologue: issue batch(0), batch(1); commit E(0) ----
  stage_W(Wt,        Wb,  0, tid, lane);
  load_E(evA, E, nbase,  0, tid);
  stage_W(Wt + 8192, Wb, 32, tid, lane);
  load_E(evB, E, nbase, 32, tid);
  VMCNT8;                    // batch(0) done: W(0) in LDS, E(0) in regs
  cvt_E(Et0, evA, tid);
  LGKM0;
  BARRAW();

  int icur = 0;              // kt % 3
  for (int kt = 0; kt < 14; kt += 2) {
    const int i1 = (icur == 2) ? 0 : icur + 1;   // (kt+1)%3
    const int i2 = (i1 == 2) ? 0 : i1 + 1;       // (kt+2)%3
    // ---- even step kt ----
    stage_W(Wt + i2 * 8192, Wb, (kt + 2) * 32, tid, lane);
    load_E(evA, E, nbase, (kt + 2) * 32, tid);
    compute_step(acc, Wt + icur * 8192, Et0, wm, wn, q, ln);
    VMCNT8;                  // batch(kt+1) done: E(kt+1) regs, W(kt+1) LDS
    cvt_E(Et1, evB, tid);
    LGKM0;
    BARRAW();
    // ---- odd step kt+1 ----
    stage_W(Wt + icur * 8192, Wb, (kt + 3) * 32, tid, lane);
    load_E(evB, E, nbase, (kt + 3) * 32, tid);
    compute_step(acc, Wt + i1 * 8192, Et1, wm, wn, q, ln);
    VMCNT8;                  // batch(kt+2) done
    cvt_E(Et0, evA, tid);
    LGKM0;
    BARRAW();
    icur = i2;
  }
  // ---- peeled kt=14 (no new issue; drain) ----
  compute_step(acc, Wt + 2 * 8192, Et0, wm, wn, q, ln);
  VMCNT0;                    // batch(15) done
  cvt_E(Et1, evB, tid);
  LGKM0;
  BARRAW();
  // ---- peeled kt=15 ----
  compute_step(acc, Wt, Et1, wm, wn, q, ln);

  if (yy == 0) {
    // Kp[n*256 + m]: m = base+q*4+r consecutive -> 8B stores
#pragma unroll
    for (int fm = 0; fm < 8; ++fm)
#pragma unroll
      for (int fn = 0; fn < 4; ++fn) {
        const int m = wm * 128 + fm * 16 + q * 4;
        const int n = nbase + wn * 64 + fn * 16 + ln;
        f32x4 v = acc[fm][fn];
        bf16x4 o;
        o[0] = (__bf16)v[0]; o[1] = (__bf16)v[1];
        o[2] = (__bf16)v[2]; o[3] = (__bf16)v[3];
        *(bf16x4*)&Kp[(size_t)n * 256 + m] = o;
      }
  } else {
    // Vtile[g][d][nl]: g = bx (one full 128-n plane per block)
    __bf16* Vp = Vtile + (size_t)bx * 32768;
#pragma unroll
    for (int fm = 0; fm < 8; ++fm)
#pragma unroll
      for (int fn = 0; fn < 4; ++fn) {
        const int nl = wn * 64 + fn * 16 + ln;
        f32x4 v = acc[fm][fn];
#pragma unroll
        for (int r = 0; r < 4; ++r) {
          const int d = wm * 128 + fm * 16 + q * 4 + r;
          Vp[d * 128 + nl] = (__bf16)v[r];
        }
      }
  }
}

// =====================================================================
// Attention, whole-tile staged (unchanged)
// =====================================================================
#define QLDS_STRIDE 264
#define PLDS_STRIDE 136
__global__ __launch_bounds__(256) void attn_kernel(
    const __bf16* __restrict__ Qw, const __bf16* __restrict__ Kp,
    const __bf16* __restrict__ Vtile, const float* __restrict__ Pb,
    __bf16* __restrict__ Pws, float* __restrict__ Opart,
    float* __restrict__ rowsum) {
  __shared__ __align__(16) __bf16 Qlds[32 * QLDS_STRIDE];   // 16896 B
  __shared__ __align__(16) __bf16 Kl[8 * 128 * 32];         // 65536 B
  __shared__ __align__(16) __bf16 Vl[4 * 256 * 32];         // 65536 B
  __shared__ __align__(16) __bf16 Plds[32 * PLDS_STRIDE];   //  8704 B

  const int tid = threadIdx.x;
  const int lane = tid & 63;
  const int w = tid >> 6;
  const int q = lane >> 4, ln = lane & 15;
  const int b = blockIdx.y;
  const int cx = blockIdx.x;
  const int n0 = cx * 128;

  // ---- stage K-tile: 4096 chunks, layout [kk][row][jc] ----
  const __bf16* Kpb = Kp + (size_t)(b * 4096 + n0) * 256;
#pragma unroll
  for (int s = 0; s < 16; ++s) {
    const int cbase = (tid & 192) + s * 256;
    const int c = cbase + lane;
    const int kk = c >> 9, row = (c >> 2) & 127, jc = c & 3;
    cp16(&Kl[cbase * 8], Kpb + (size_t)row * 256 + kk * 32 + jc * 8);
  }
  // ---- stage V-plane: 4096 chunks, layout [kk][d][jc] ----
  const __bf16* Vplane = Vtile + (size_t)(b * 32 + cx) * 32768;
#pragma unroll
  for (int s = 0; s < 16; ++s) {
    const int cbase = (tid & 192) + s * 256;
    const int c = cbase + lane;
    const int kk = c >> 10, d = (c >> 2) & 255, jc = c & 3;
    cp16(&Vl[cbase * 8], Vplane + (size_t)d * 128 + kk * 32 + jc * 8);
  }
  // ---- stage Q_b [32 x 256] (reg -> padded LDS) ----
  const __bf16* Qb = Qw + (size_t)b * 32 * 256;
#pragma unroll
  for (int s = 0; s < 4; ++s) {
    const int c = tid + s * 256;
    const int row = c >> 5, col = (c & 31) * 8;
    bf16x8 v = *(const bf16x8*)(Qb + (size_t)c * 8);
    *(bf16x8*)&Qlds[row * QLDS_STRIDE + col] = v;
  }
  __syncthreads();

  // ---- QK^T ----
  f32x4 acc[2][2] = {};
  for (int kk = 0; kk < 8; ++kk) {
    bf16x8 a0 = *(const bf16x8*)&Qlds[(ln) * QLDS_STRIDE + kk * 32 + q * 8];
    bf16x8 a1 = *(const bf16x8*)&Qlds[(16 + ln) * QLDS_STRIDE + kk * 32 + q * 8];
    bf16x8 b0 = *(const bf16x8*)&Kl[kk * 4096 + (w * 32 + ln) * 32 + q * 8];
    bf16x8 b1 = *(const bf16x8*)&Kl[kk * 4096 + (w * 32 + 16 + ln) * 32 + q * 8];
    acc[0][0] = __builtin_amdgcn_mfma_f32_16x16x32_bf16(a0, b0, acc[0][0], 0, 0, 0);
    acc[0][1] = __builtin_amdgcn_mfma_f32_16x16x32_bf16(a0, b1, acc[0][1], 0, 0, 0);
    acc[1][0] = __builtin_amdgcn_mfma_f32_16x16x32_bf16(a1, b0, acc[1][0], 0, 0, 0);
    acc[1][1] = __builtin_amdgcn_mfma_f32_16x16x32_bf16(a1, b1, acc[1][1], 0, 0, 0);
  }

  // ---- P = exp(S/16 + logP) ----
  float lp[2];
#pragma unroll
  for (int fn = 0; fn < 2; ++fn) {
    const int n = n0 + w * 32 + fn * 16 + ln;
    float p = Pb[b * 4096 + n];
    p = fminf(fmaxf(p, 0.1f), 0.9f);
    lp[fn] = __logf(p);
  }
  float rs[2][4] = {};
#pragma unroll
  for (int fm = 0; fm < 2; ++fm) {
#pragma unroll
    for (int fn = 0; fn < 2; ++fn) {
      f32x4 s = acc[fm][fn];
#pragma unroll
      for (int r = 0; r < 4; ++r) {
        const float pv = __expf(s[r] * 0.0625f + lp[fn]);
        const int i = fm * 16 + q * 4 + r;
        const int nn = w * 32 + fn * 16 + ln;
        const __bf16 pbv = (__bf16)pv;
        Pws[(size_t)(b * 32 + i) * 4096 + n0 + nn] = pbv;
        Plds[i * PLDS_STRIDE + nn] = pbv;
        rs[fm][r] += pv;
      }
    }
  }
#pragma unroll
  for (int m = 1; m < 16; m <<= 1)
#pragma unroll
    for (int fm = 0; fm < 2; ++fm)
#pragma unroll
      for (int r = 0; r < 4; ++r)
        rs[fm][r] += __shfl_xor(rs[fm][r], m, 64);
  if (ln == 0) {
#pragma unroll
    for (int fm = 0; fm < 2; ++fm)
#pragma unroll
      for (int r = 0; r < 4; ++r)
        atomicAdd(&rowsum[b * 32 + fm * 16 + q * 4 + r], rs[fm][r]);
  }
  __syncthreads();

  // ---- PV ----
  f32x4 acc2[2][4] = {};
  for (int kk = 0; kk < 4; ++kk) {
    bf16x8 pa0 = *(const bf16x8*)&Plds[(ln) * PLDS_STRIDE + kk * 32 + q * 8];
    bf16x8 pa1 = *(const bf16x8*)&Plds[(16 + ln) * PLDS_STRIDE + kk * 32 + q * 8];
#pragma unroll
    for (int fd = 0; fd < 4; ++fd) {
      bf16x8 vb = *(const bf16x8*)&Vl[kk * 8192 + (w * 64 + fd * 16 + ln) * 32 + q * 8];
      acc2[0][fd] = __builtin_amdgcn_mfma_f32_16x16x32_bf16(pa0, vb, acc2[0][fd], 0, 0, 0);
      acc2[1][fd] = __builtin_amdgcn_mfma_f32_16x16x32_bf16(pa1, vb, acc2[1][fd], 0, 0, 0);
    }
  }
  float* Op = Opart + (size_t)cx * 131072;
#pragma unroll
  for (int fm = 0; fm < 2; ++fm)
#pragma unroll
    for (int fd = 0; fd < 4; ++fd)
#pragma unroll
      for (int r = 0; r < 4; ++r) {
        const int i = fm * 16 + q * 4 + r;
        const int d = w * 64 + fd * 16 + ln;
        Op[(size_t)(b * 32 + i) * 256 + d] = acc2[fm][fd][r];
      }
}

// =====================================================================
// norm_p (unchanged)
// =====================================================================
__global__ __launch_bounds__(256) void norm_p(const __bf16* __restrict__ Pws,
                                              const float* __restrict__ rowsum,
                                              float* __restrict__ Aout) {
  const size_t idx = ((size_t)blockIdx.x * 256 + threadIdx.x) * 4;
  const int row = (int)(idx >> 12);
  const float invs = 1.0f / rowsum[row];
  bf16x4 p = *(const bf16x4*)(Pws + idx);
  f32x4 o;
  o[0] = (float)p[0] * invs; o[1] = (float)p[1] * invs;
  o[2] = (float)p[2] * invs; o[3] = (float)p[3] * invs;
  *(f32x4*)(Aout + idx) = o;
}

// =====================================================================
// final (unchanged)
// =====================================================================
__global__ __launch_bounds__(256) void final_kernel(const float* __restrict__ Opart,
                                                    const float* __restrict__ rowsum,
                                                    const float* __restrict__ Wo,
                                                    float* __restrict__ Fout) {
  __shared__ float fl[256];
  __shared__ float redbuf[4];
  const int row = blockIdx.x;
  const int t = threadIdx.x;
  float s = 0.f;
#pragma unroll
  for (int c = 0; c < 32; ++c)
    s += Opart[(size_t)c * 131072 + (size_t)row * 256 + t];
  fl[t] = s;
  __syncthreads();
  const float invs = 1.0f / rowsum[row];
  float f2[2];
#pragma unroll
  for (int h = 0; h < 2; ++h) {
    const int m = t + h * 256;
    const float* wr = Wo + (size_t)m * 256;
    float dot = 0.f;
    for (int d = 0; d < 256; d += 4) {
      f32x4 wv = *(const f32x4*)(wr + d);
      dot += wv[0] * fl[d] + wv[1] * fl[d + 1] + wv[2] * fl[d + 2] + wv[3] * fl[d + 3];
    }
    f2[h] = dot * invs;
  }
  float ps = f2[0] * f2[0] + f2[1] * f2[1];
#pragma unroll
  for (int m = 1; m < 64; m <<= 1) ps += __shfl_xor(ps, m, 64);
  if ((t & 63) == 0) redbuf[t >> 6] = ps;
  __syncthreads();
  const float tot = redbuf[0] + redbuf[1] + redbuf[2] + redbuf[3];
  const float sc = 1.0f / (sqrtf(tot) + 1e-8f);
  Fout[(size_t)row * 512 + t] = f2[0] * sc;
  Fout[(size_t)row * 512 + t + 256] = f2[1] * sc;
}

// =====================================================================
extern "C" void kernel_launch(void* const* d_in, const int* in_sizes, int n_in,
                              void* d_out, int out_size, void* d_ws, size_t ws_size,
                              hipStream_t stream) {
  const float* E  = (const float*)d_in[0];  // [16,4096,512]
  const float* T  = (const float*)d_in[1];  // [16,32,512]
  const float* Pb = (const float*)d_in[2];  // [16,4096]
  const float* Wq = (const float*)d_in[3];  // [256,512]
  const float* Wk = (const float*)d_in[4];
  const float* Wv = (const float*)d_in[5];
  const float* Wo = (const float*)d_in[6];  // [512,256]

  float* out  = (float*)d_out;
  float* Fout = out;             // [512][512] f32
  float* Aout = out + 262144;    // [512][4096] f32

  char* ws = (char*)d_ws;
  __bf16* Kp    = (__bf16*)ws;                  // [65536][256] bf16  33554432 B
  __bf16* Vtile = (__bf16*)(ws + 33554432);     // [512][256][128]    33554432 B
  __bf16* Pws   = (__bf16*)(ws + 67108864);     // [512][4096] bf16    4194304 B
  float*  Opart = (float*)(ws + 71303168);      // [32][512][256] f32 16777216 B
  __bf16* Tbf   = (__bf16*)(ws + 88080384);     //                      524288 B
  __bf16* Wqb   = (__bf16*)(ws + 88604672);     //                      262144 B
  __bf16* Wkvb  = (__bf16*)(ws + 88866816);     //                      524288 B
  __bf16* Qw    = (__bf16*)(ws + 89391104);     // [512][256] bf16      262144 B
  float*  rowsum = (float*)(ws + 89653248);     // [512] f32 (2048 B)

  hipMemsetAsync(rowsum, 0, 2048, stream);

  cvt_small<<<640, 256, 0, stream>>>(Wq, Wk, Wv, T, Wqb, Wkvb, Tbf);

  // Kp (y=0), Vtile (y=1), Qw (y=0, x>=512) in one launch
  gemm_kv<<<dim3(520, 2), 256, 0, stream>>>(E, Wkvb, Wqb, Tbf, Kp, Vtile, Qw);

  attn_kernel<<<dim3(32, 16), 256, 0, stream>>>(Qw, Kp, Vtile, Pb, Pws, Opart, rowsum);
  norm_p<<<2048, 256, 0, stream>>>(Pws, rowsum, Aout);
  final_kernel<<<512, 256, 0, stream>>>(Opart, rowsum, Wo, Fout);
}

// Round 5
// 335.076 us; speedup vs baseline: 1.1373x; 1.0248x over previous
//
#include <hip/hip_runtime.h>

// ---------- types ----------
typedef __bf16 bf16x8 __attribute__((ext_vector_type(8)));
typedef __bf16 bf16x4 __attribute__((ext_vector_type(4)));
typedef float  f32x4  __attribute__((ext_vector_type(4)));

// async global->LDS, 16B per lane; LDS dest = wave-uniform base + lane*16
__device__ __forceinline__ void cp16(void* lds, const void* g) {
  __builtin_amdgcn_global_load_lds(
      (const __attribute__((address_space(1))) unsigned int*)g,
      (__attribute__((address_space(3))) unsigned int*)lds, 16, 0, 0);
}

#define VMCNT6 asm volatile("s_waitcnt vmcnt(6)" ::: "memory")
#define VMCNT0 asm volatile("s_waitcnt vmcnt(0)" ::: "memory")
#define LGKM0  asm volatile("s_waitcnt lgkmcnt(0)" ::: "memory")
#define BARRAW __builtin_amdgcn_s_barrier

// =====================================================================
// Fused small conversions: Wq->Wqb, Wk->Wkvb[0:], Wv->Wkvb[131072:], T->Tbf
// =====================================================================
__global__ __launch_bounds__(256) void cvt_small(const float* __restrict__ Wq,
                                                 const float* __restrict__ Wk,
                                                 const float* __restrict__ Wv,
                                                 const float* __restrict__ T,
                                                 __bf16* __restrict__ Wqb,
                                                 __bf16* __restrict__ Wkvb,
                                                 __bf16* __restrict__ Tbf) {
  const int idx = (blockIdx.x * 256 + threadIdx.x) * 4;
  const float* src;
  __bf16* dst;
  int o;
  if (idx < 131072)      { o = idx;          src = Wq; dst = Wqb; }
  else if (idx < 262144) { o = idx - 131072; src = Wk; dst = Wkvb; }
  else if (idx < 393216) { o = idx - 262144; src = Wv; dst = Wkvb + 131072; }
  else                   { o = idx - 393216; src = T;  dst = Tbf; }
  f32x4 v = *(const f32x4*)(src + o);
  bf16x4 b;
  b[0] = (__bf16)v[0]; b[1] = (__bf16)v[1];
  b[2] = (__bf16)v[2]; b[3] = (__bf16)v[3];
  *(bf16x4*)(dst + o) = b;
}

// =====================================================================
// gemm_kv v6: FUSED K+V. 512 threads (8 waves), M=512 (full Wkv) x
// N=128 per block, BK=32, acc[8][4]=128 AGPR/wave. Each E slab is read
// ONCE per block (round-4 post-mortem: the 2x E stream was the shared
// invariant across all four stalled schedules). W staged 32KB/step from
// L2, E 16KB/step from HBM. v5 counted-vmcnt 2-ahead pipeline kept:
// W triple-buffer cp16, E double reg + double LDS; vmcnt(6) keeps the
// newest 6-op batch in flight; RAW s_barrier, no vmcnt drain in loop.
//   wm<2  -> Kp[n][m]       (rows 0..255 of Wkv = Wk)
//   wm>=2 -> Vtile[bx][d][nl] (rows 256..511 = Wv)
//   bx in [512,520): Qw = T@Wq^T (tid<256 compute, all threads barrier)
// =====================================================================
#define ETS 40   // Et row stride (elems): 80 B -> 8 bank-groups, 2-way free
__device__ __forceinline__ void stage_W(__bf16* Wdst, const __bf16* Wb,
                                        int k0, int tid, int lane) {
#pragma unroll
  for (int s = 0; s < 4; ++s) {
    const int cbase = (tid & 448) + s * 512;   // wave-uniform chunk base
    const int p = cbase + lane;                // 0..2047
    const int sp = p >> 3;
    const int slot = (p & 7) ^ (sp & 7);
    const int row = sp * 2 + (slot >> 2);      // 0..511
    const int kc = slot & 3;
    cp16(&Wdst[cbase * 8], Wb + (size_t)row * 512 + k0 + kc * 8);
  }
}
__device__ __forceinline__ void load_E(f32x4* ev, const float* E,
                                       int nbase, int k0, int tid) {
#pragma unroll
  for (int s = 0; s < 2; ++s) {
    const int c = tid + s * 512;               // 0..1023
    ev[s] = *(const f32x4*)(E + (size_t)(nbase + (c >> 3)) * 512 + k0 + (c & 7) * 4);
  }
}
__device__ __forceinline__ void cvt_E(__bf16* Edst, const f32x4* ev, int tid) {
#pragma unroll
  for (int s = 0; s < 2; ++s) {
    const int c = tid + s * 512;
    bf16x4 b4;
    b4[0] = (__bf16)ev[s][0]; b4[1] = (__bf16)ev[s][1];
    b4[2] = (__bf16)ev[s][2]; b4[3] = (__bf16)ev[s][3];
    *(bf16x4*)&Edst[(c >> 3) * ETS + (c & 7) * 4] = b4;
  }
}
__device__ __forceinline__ void compute_step(f32x4 (&acc)[8][4], const __bf16* Wc,
                                             const __bf16* Ec, int wm, int wn,
                                             int q, int ln) {
  bf16x8 bfr[4];
#pragma unroll
  for (int fn = 0; fn < 4; ++fn)
    bfr[fn] = *(const bf16x8*)&Ec[(wn * 64 + fn * 16 + ln) * ETS + q * 8];
#pragma unroll
  for (int fm = 0; fm < 8; ++fm) {
    const int row = wm * 128 + fm * 16 + ln;   // 0..511
    const int slot = (((row & 1) << 2) | q) ^ ((row >> 1) & 7);
    bf16x8 af = *(const bf16x8*)&Wc[(row >> 1) * 64 + slot * 8];
#pragma unroll
    for (int fn = 0; fn < 4; ++fn)
      acc[fm][fn] = __builtin_amdgcn_mfma_f32_16x16x32_bf16(
          af, bfr[fn], acc[fm][fn], 0, 0, 0);
  }
}

__global__ __launch_bounds__(512, 2) void gemm_kv(const float* __restrict__ E,
                                                  const __bf16* __restrict__ Wkv,
                                                  const __bf16* __restrict__ Wqb,
                                                  const __bf16* __restrict__ Tbf,
                                                  __bf16* __restrict__ Kp,
                                                  __bf16* __restrict__ Vtile,
                                                  __bf16* __restrict__ Qw) {
  __shared__ __align__(16) char smem[118784];
  __bf16* Wt = (__bf16*)smem;              // 3 x [512][32] bf16 = 98304 B
  __bf16* Et = (__bf16*)(smem + 98304);    // 2 x [128][ETS] bf16 = 20480 B

  const int tid = threadIdx.x;
  const int lane = tid & 63;
  const int q = lane >> 4, ln = lane & 15;
  const int w = tid >> 6;                  // 0..7
  const int bx = blockIdx.x;
  const int wm = w >> 1, wn = w & 1;       // wm 0..3, wn 0..1

  if (bx >= 512) {
    // ---- small Q GEMM: tid<256 compute, ALL threads hit barriers ----
    const int t = bx - 512;                // 0..7
    __bf16* At = Wt;                       // 128x32
    __bf16* Bt = Wt + 4096;                // 128x32
    const int nbase = (t & 3) * 128;
    const int mbase = (t >> 2) * 128;
    const int qwm = (tid >> 7) & 1, qwn = (tid >> 6) & 1;  // for tid<256: w>>1, w&1
    f32x4 acc[4][4] = {};
    for (int kt = 0; kt < 16; ++kt) {
      const int k0 = kt * 32;
      __syncthreads();
      if (tid < 256) {
#pragma unroll
        for (int s = 0; s < 2; ++s) {
          const int cbase = (tid & 192) + s * 256;
          const int c = cbase + lane;
          const int row = c >> 2;
          const int kc = (c & 3) * 8;
          cp16(&At[cbase * 8], Wqb + (size_t)(mbase + row) * 512 + k0 + kc);
          cp16(&Bt[cbase * 8], Tbf + (size_t)(nbase + row) * 512 + k0 + kc);
        }
      }
      __syncthreads();
      if (tid < 256) {
        bf16x8 af[4], bfr[4];
#pragma unroll
        for (int f = 0; f < 4; ++f) {
          af[f]  = *(const bf16x8*)&At[(qwm * 64 + f * 16 + ln) * 32 + q * 8];
          bfr[f] = *(const bf16x8*)&Bt[(qwn * 64 + f * 16 + ln) * 32 + q * 8];
        }
#pragma unroll
        for (int fm = 0; fm < 4; ++fm)
#pragma unroll
          for (int fn = 0; fn < 4; ++fn)
            acc[fm][fn] = __builtin_amdgcn_mfma_f32_16x16x32_bf16(
                af[fm], bfr[fn], acc[fm][fn], 0, 0, 0);
      }
    }
    if (tid < 256) {
#pragma unroll
      for (int fm = 0; fm < 4; ++fm)
#pragma unroll
        for (int fn = 0; fn < 4; ++fn) {
          const int m = mbase + qwm * 64 + fm * 16 + q * 4;
          const int n = nbase + qwn * 64 + fn * 16 + ln;
          f32x4 v = acc[fm][fn];
          bf16x4 o;
          o[0] = (__bf16)v[0]; o[1] = (__bf16)v[1];
          o[2] = (__bf16)v[2]; o[3] = (__bf16)v[3];
          *(bf16x4*)&Qw[(size_t)n * 256 + m] = o;
        }
    }
    return;
  }

  // ---- fused KV path: 512m x 128n, 2-ahead counted-vmcnt pipeline ----
  const int nbase = bx * 128;
  const __bf16* Wb = Wkv;                  // full 512 rows x 512
  __bf16* Et0 = Et;
  __bf16* Et1 = Et + 128 * ETS;

  f32x4 acc[8][4] = {};
  f32x4 evA[2], evB[2];

  // ---- prologue: issue batch(0), batch(1); commit E(0) ----
  stage_W(Wt,         Wb,  0, tid, lane);
  load_E(evA, E, nbase,  0, tid);
  stage_W(Wt + 16384, Wb, 32, tid, lane);
  load_E(evB, E, nbase, 32, tid);
  VMCNT6;                    // batch(0) done: W(0) in LDS, E(0) in regs
  cvt_E(Et0, evA, tid);
  LGKM0;
  BARRAW();

  int icur = 0;              // kt % 3
  for (int kt = 0; kt < 14; kt += 2) {
    const int i1 = (icur == 2) ? 0 : icur + 1;   // (kt+1)%3
    const int i2 = (i1 == 2) ? 0 : i1 + 1;       // (kt+2)%3
    // ---- even step kt ----
    stage_W(Wt + i2 * 16384, Wb, (kt + 2) * 32, tid, lane);
    load_E(evA, E, nbase, (kt + 2) * 32, tid);
    compute_step(acc, Wt + icur * 16384, Et0, wm, wn, q, ln);
    VMCNT6;                  // batch(kt+1) done
    cvt_E(Et1, evB, tid);
    LGKM0;
    BARRAW();
    // ---- odd step kt+1 ----
    stage_W(Wt + icur * 16384, Wb, (kt + 3) * 32, tid, lane);
    load_E(evB, E, nbase, (kt + 3) * 32, tid);
    compute_step(acc, Wt + i1 * 16384, Et1, wm, wn, q, ln);
    VMCNT6;                  // batch(kt+2) done
    cvt_E(Et0, evA, tid);
    LGKM0;
    BARRAW();
    icur = i2;
  }
  // ---- peeled kt=14 (no new issue; drain) ----
  compute_step(acc, Wt + 2 * 16384, Et0, wm, wn, q, ln);
  VMCNT0;                    // batch(15) done
  cvt_E(Et1, evB, tid);
  LGKM0;
  BARRAW();
  // ---- peeled kt=15 ----
  compute_step(acc, Wt, Et1, wm, wn, q, ln);

  if (wm < 2) {
    // Kp[n*256 + m]: m = wm*128+fm*16+q*4 consecutive -> 8B stores
#pragma unroll
    for (int fm = 0; fm < 8; ++fm)
#pragma unroll
      for (int fn = 0; fn < 4; ++fn) {
        const int m = wm * 128 + fm * 16 + q * 4;
        const int n = nbase + wn * 64 + fn * 16 + ln;
        f32x4 v = acc[fm][fn];
        bf16x4 o;
        o[0] = (__bf16)v[0]; o[1] = (__bf16)v[1];
        o[2] = (__bf16)v[2]; o[3] = (__bf16)v[3];
        *(bf16x4*)&Kp[(size_t)n * 256 + m] = o;
      }
  } else {
    // Vtile[g=bx][d][nl]: d' rows 256..511 = Wv
    __bf16* Vp = Vtile + (size_t)bx * 32768;
#pragma unroll
    for (int fm = 0; fm < 8; ++fm)
#pragma unroll
      for (int fn = 0; fn < 4; ++fn) {
        const int nl = wn * 64 + fn * 16 + ln;
        f32x4 v = acc[fm][fn];
#pragma unroll
        for (int r = 0; r < 4; ++r) {
          const int d = (wm - 2) * 128 + fm * 16 + q * 4 + r;
          Vp[d * 128 + nl] = (__bf16)v[r];
        }
      }
  }
}

// =====================================================================
// Attention v2: V staged to REGISTERS (was LDS round-trip read exactly
// once -> pure overhead, Common-mistake #7). V loads issued FIRST so
// they fly under K cp16 + Q staging. PV B-operand now register-resident
// (deletes 16 ds_read_b128/thread + 64KB LDS). LDS 157 -> 91 KB.
// =====================================================================
#define QLDS_STRIDE 264
#define PLDS_STRIDE 136
__global__ __launch_bounds__(256) void attn_kernel(
    const __bf16* __restrict__ Qw, const __bf16* __restrict__ Kp,
    const __bf16* __restrict__ Vtile, const float* __restrict__ Pb,
    __bf16* __restrict__ Pws, float* __restrict__ Opart,
    float* __restrict__ rowsum) {
  __shared__ __align__(16) __bf16 Qlds[32 * QLDS_STRIDE];   // 16896 B
  __shared__ __align__(16) __bf16 Kl[8 * 128 * 32];         // 65536 B
  __shared__ __align__(16) __bf16 Plds[32 * PLDS_STRIDE];   //  8704 B

  const int tid = threadIdx.x;
  const int lane = tid & 63;
  const int w = tid >> 6;
  const int q = lane >> 4, ln = lane & 15;
  const int b = blockIdx.y;
  const int cx = blockIdx.x;
  const int n0 = cx * 128;

  // ---- V -> registers, issued first (oldest in VMEM queue) ----
  const __bf16* Vplane = Vtile + (size_t)(b * 32 + cx) * 32768;
  bf16x8 vreg[4][4];
#pragma unroll
  for (int kk = 0; kk < 4; ++kk)
#pragma unroll
    for (int fd = 0; fd < 4; ++fd)
      vreg[kk][fd] = *(const bf16x8*)&Vplane[
          (size_t)(w * 64 + fd * 16 + ln) * 128 + kk * 32 + q * 8];

  // ---- stage K-tile: 4096 chunks, layout [kk][row][jc] ----
  const __bf16* Kpb = Kp + (size_t)(b * 4096 + n0) * 256;
#pragma unroll
  for (int s = 0; s < 16; ++s) {
    const int cbase = (tid & 192) + s * 256;
    const int c = cbase + lane;
    const int kk = c >> 9, row = (c >> 2) & 127, jc = c & 3;
    cp16(&Kl[cbase * 8], Kpb + (size_t)row * 256 + kk * 32 + jc * 8);
  }
  // ---- stage Q_b [32 x 256] (reg -> padded LDS) ----
  const __bf16* Qb = Qw + (size_t)b * 32 * 256;
#pragma unroll
  for (int s = 0; s < 4; ++s) {
    const int c = tid + s * 256;
    const int row = c >> 5, col = (c & 31) * 8;
    bf16x8 v = *(const bf16x8*)(Qb + (size_t)c * 8);
    *(bf16x8*)&Qlds[row * QLDS_STRIDE + col] = v;
  }
  __syncthreads();

  // ---- QK^T ----
  f32x4 acc[2][2] = {};
  for (int kk = 0; kk < 8; ++kk) {
    bf16x8 a0 = *(const bf16x8*)&Qlds[(ln) * QLDS_STRIDE + kk * 32 + q * 8];
    bf16x8 a1 = *(const bf16x8*)&Qlds[(16 + ln) * QLDS_STRIDE + kk * 32 + q * 8];
    bf16x8 b0 = *(const bf16x8*)&Kl[kk * 4096 + (w * 32 + ln) * 32 + q * 8];
    bf16x8 b1 = *(const bf16x8*)&Kl[kk * 4096 + (w * 32 + 16 + ln) * 32 + q * 8];
    acc[0][0] = __builtin_amdgcn_mfma_f32_16x16x32_bf16(a0, b0, acc[0][0], 0, 0, 0);
    acc[0][1] = __builtin_amdgcn_mfma_f32_16x16x32_bf16(a0, b1, acc[0][1], 0, 0, 0);
    acc[1][0] = __builtin_amdgcn_mfma_f32_16x16x32_bf16(a1, b0, acc[1][0], 0, 0, 0);
    acc[1][1] = __builtin_amdgcn_mfma_f32_16x16x32_bf16(a1, b1, acc[1][1], 0, 0, 0);
  }

  // ---- P = exp(S/16 + logP) ----
  float lp[2];
#pragma unroll
  for (int fn = 0; fn < 2; ++fn) {
    const int n = n0 + w * 32 + fn * 16 + ln;
    float p = Pb[b * 4096 + n];
    p = fminf(fmaxf(p, 0.1f), 0.9f);
    lp[fn] = __logf(p);
  }
  float rs[2][4] = {};
#pragma unroll
  for (int fm = 0; fm < 2; ++fm) {
#pragma unroll
    for (int fn = 0; fn < 2; ++fn) {
      f32x4 s = acc[fm][fn];
#pragma unroll
      for (int r = 0; r < 4; ++r) {
        const float pv = __expf(s[r] * 0.0625f + lp[fn]);
        const int i = fm * 16 + q * 4 + r;
        const int nn = w * 32 + fn * 16 + ln;
        const __bf16 pbv = (__bf16)pv;
        Pws[(size_t)(b * 32 + i) * 4096 + n0 + nn] = pbv;
        Plds[i * PLDS_STRIDE + nn] = pbv;
        rs[fm][r] += pv;
      }
    }
  }
#pragma unroll
  for (int m = 1; m < 16; m <<= 1)
#pragma unroll
    for (int fm = 0; fm < 2; ++fm)
#pragma unroll
      for (int r = 0; r < 4; ++r)
        rs[fm][r] += __shfl_xor(rs[fm][r], m, 64);
  if (ln == 0) {
#pragma unroll
    for (int fm = 0; fm < 2; ++fm)
#pragma unroll
      for (int r = 0; r < 4; ++r)
        atomicAdd(&rowsum[b * 32 + fm * 16 + q * 4 + r], rs[fm][r]);
  }
  __syncthreads();

  // ---- PV: B-operand from registers ----
  f32x4 acc2[2][4] = {};
#pragma unroll
  for (int kk = 0; kk < 4; ++kk) {
    bf16x8 pa0 = *(const bf16x8*)&Plds[(ln) * PLDS_STRIDE + kk * 32 + q * 8];
    bf16x8 pa1 = *(const bf16x8*)&Plds[(16 + ln) * PLDS_STRIDE + kk * 32 + q * 8];
#pragma unroll
    for (int fd = 0; fd < 4; ++fd) {
      acc2[0][fd] = __builtin_amdgcn_mfma_f32_16x16x32_bf16(pa0, vreg[kk][fd], acc2[0][fd], 0, 0, 0);
      acc2[1][fd] = __builtin_amdgcn_mfma_f32_16x16x32_bf16(pa1, vreg[kk][fd], acc2[1][fd], 0, 0, 0);
    }
  }
  float* Op = Opart + (size_t)cx * 131072;
#pragma unroll
  for (int fm = 0; fm < 2; ++fm)
#pragma unroll
    for (int fd = 0; fd < 4; ++fd)
#pragma unroll
      for (int r = 0; r < 4; ++r) {
        const int i = fm * 16 + q * 4 + r;
        const int d = w * 64 + fd * 16 + ln;
        Op[(size_t)(b * 32 + i) * 256 + d] = acc2[fm][fd][r];
      }
}

// =====================================================================
// norm_p (unchanged)
// =====================================================================
__global__ __launch_bounds__(256) void norm_p(const __bf16* __restrict__ Pws,
                                              const float* __restrict__ rowsum,
                                              float* __restrict__ Aout) {
  const size_t idx = ((size_t)blockIdx.x * 256 + threadIdx.x) * 4;
  const int row = (int)(idx >> 12);
  const float invs = 1.0f / rowsum[row];
  bf16x4 p = *(const bf16x4*)(Pws + idx);
  f32x4 o;
  o[0] = (float)p[0] * invs; o[1] = (float)p[1] * invs;
  o[2] = (float)p[2] * invs; o[3] = (float)p[3] * invs;
  *(f32x4*)(Aout + idx) = o;
}

// =====================================================================
// final (unchanged)
// =====================================================================
__global__ __launch_bounds__(256) void final_kernel(const float* __restrict__ Opart,
                                                    const float* __restrict__ rowsum,
                                                    const float* __restrict__ Wo,
                                                    float* __restrict__ Fout) {
  __shared__ float fl[256];
  __shared__ float redbuf[4];
  const int row = blockIdx.x;
  const int t = threadIdx.x;
  float s = 0.f;
#pragma unroll
  for (int c = 0; c < 32; ++c)
    s += Opart[(size_t)c * 131072 + (size_t)row * 256 + t];
  fl[t] = s;
  __syncthreads();
  const float invs = 1.0f / rowsum[row];
  float f2[2];
#pragma unroll
  for (int h = 0; h < 2; ++h) {
    const int m = t + h * 256;
    const float* wr = Wo + (size_t)m * 256;
    float dot = 0.f;
    for (int d = 0; d < 256; d += 4) {
      f32x4 wv = *(const f32x4*)(wr + d);
      dot += wv[0] * fl[d] + wv[1] * fl[d + 1] + wv[2] * fl[d + 2] + wv[3] * fl[d + 3];
    }
    f2[h] = dot * invs;
  }
  float ps = f2[0] * f2[0] + f2[1] * f2[1];
#pragma unroll
  for (int m = 1; m < 64; m <<= 1) ps += __shfl_xor(ps, m, 64);
  if ((t & 63) == 0) redbuf[t >> 6] = ps;
  __syncthreads();
  const float tot = redbuf[0] + redbuf[1] + redbuf[2] + redbuf[3];
  const float sc = 1.0f / (sqrtf(tot) + 1e-8f);
  Fout[(size_t)row * 512 + t] = f2[0] * sc;
  Fout[(size_t)row * 512 + t + 256] = f2[1] * sc;
}

// =====================================================================
extern "C" void kernel_launch(void* const* d_in, const int* in_sizes, int n_in,
                              void* d_out, int out_size, void* d_ws, size_t ws_size,
                              hipStream_t stream) {
  const float* E  = (const float*)d_in[0];  // [16,4096,512]
  const float* T  = (const float*)d_in[1];  // [16,32,512]
  const float* Pb = (const float*)d_in[2];  // [16,4096]
  const float* Wq = (const float*)d_in[3];  // [256,512]
  const float* Wk = (const float*)d_in[4];
  const float* Wv = (const float*)d_in[5];
  const float* Wo = (const float*)d_in[6];  // [512,256]

  float* out  = (float*)d_out;
  float* Fout = out;             // [512][512] f32
  float* Aout = out + 262144;    // [512][4096] f32

  char* ws = (char*)d_ws;
  __bf16* Kp    = (__bf16*)ws;                  // [65536][256] bf16  33554432 B
  __bf16* Vtile = (__bf16*)(ws + 33554432);     // [512][256][128]    33554432 B
  __bf16* Pws   = (__bf16*)(ws + 67108864);     // [512][4096] bf16    4194304 B
  float*  Opart = (float*)(ws + 71303168);      // [32][512][256] f32 16777216 B
  __bf16* Tbf   = (__bf16*)(ws + 88080384);     //                      524288 B
  __bf16* Wqb   = (__bf16*)(ws + 88604672);     //                      262144 B
  __bf16* Wkvb  = (__bf16*)(ws + 88866816);     //                      524288 B
  __bf16* Qw    = (__bf16*)(ws + 89391104);     // [512][256] bf16      262144 B
  float*  rowsum = (float*)(ws + 89653248);     // [512] f32 (2048 B)

  hipMemsetAsync(rowsum, 0, 2048, stream);

  cvt_small<<<640, 256, 0, stream>>>(Wq, Wk, Wv, T, Wqb, Wkvb, Tbf);

  // Fused KV (bx<512) + Qw (bx in [512,520)) in one launch, 512 thr
  gemm_kv<<<dim3(520, 1), 512, 0, stream>>>(E, Wkvb, Wqb, Tbf, Kp, Vtile, Qw);

  attn_kernel<<<dim3(32, 16), 256, 0, stream>>>(Qw, Kp, Vtile, Pb, Pws, Opart, rowsum);
  norm_p<<<2048, 256, 0, stream>>>(Pws, rowsum, Aout);
  final_kernel<<<512, 256, 0, stream>>>(Opart, rowsum, Wo, Fout);
}

// Round 6
// 300.134 us; speedup vs baseline: 1.2697x; 1.1164x over previous
//
#include <hip/hip_runtime.h>

// ---------- types ----------
typedef __bf16 bf16x8 __attribute__((ext_vector_type(8)));
typedef __bf16 bf16x4 __attribute__((ext_vector_type(4)));
typedef float  f32x4  __attribute__((ext_vector_type(4)));

// async global->LDS, 16B per lane; LDS dest = wave-uniform base + lane*16
__device__ __forceinline__ void cp16(void* lds, const void* g) {
  __builtin_amdgcn_global_load_lds(
      (const __attribute__((address_space(1))) unsigned int*)g,
      (__attribute__((address_space(3))) unsigned int*)lds, 16, 0, 0);
}

#define VMCNT0 asm volatile("s_waitcnt vmcnt(0)" ::: "memory")
#define LGKM0  asm volatile("s_waitcnt lgkmcnt(0)" ::: "memory")
#define BARRAW __builtin_amdgcn_s_barrier
#define MFMA   __builtin_amdgcn_mfma_f32_16x16x32_bf16

// =====================================================================
// ALGORITHM (round-5 restructure): K/V are never materialized.
//   scores = (Q@Wk) . E   (contract DIM=512, not D=256 against K)
//   F_unnorm = P @ E      (fused with scores pass; E read ONCE)
//   Fout = L2norm((F_unnorm @ Wv^T) @ Wo^T)   (rowsum cancels in L2 norm)
//   Aout = Pws / rowsum   (unchanged)
// FLOPs 38 -> ~5 GFLOP; HBM ~175 MB total.
// =====================================================================

// =====================================================================
// cvt_small: Wq->Wqb bf16, T->Tbf bf16, Wk->WkT bf16 [512m][256d],
//            Wv->WvT f32 [512m][256d]  (4x4 register transposes)
// =====================================================================
__global__ __launch_bounds__(256) void cvt_small(const float* __restrict__ Wq,
                                                 const float* __restrict__ Wk,
                                                 const float* __restrict__ Wv,
                                                 const float* __restrict__ T,
                                                 __bf16* __restrict__ Wqb,
                                                 __bf16* __restrict__ Tbf,
                                                 __bf16* __restrict__ WkT,
                                                 float* __restrict__ WvT) {
  const int idx = blockIdx.x * 256 + threadIdx.x;
  if (idx < 32768) {
    const int o = idx * 4;
    f32x4 v = *(const f32x4*)(Wq + o);
    bf16x4 b;
    b[0] = (__bf16)v[0]; b[1] = (__bf16)v[1];
    b[2] = (__bf16)v[2]; b[3] = (__bf16)v[3];
    *(bf16x4*)(Wqb + o) = b;
  } else if (idx < 98304) {
    const int o = (idx - 32768) * 4;
    f32x4 v = *(const f32x4*)(T + o);
    bf16x4 b;
    b[0] = (__bf16)v[0]; b[1] = (__bf16)v[1];
    b[2] = (__bf16)v[2]; b[3] = (__bf16)v[3];
    *(bf16x4*)(Tbf + o) = b;
  } else if (idx < 106496) {
    const int t2 = idx - 98304;                 // Wk [256 d][512 m] -> WkT
    const int d0 = (t2 >> 7) * 4, m0 = (t2 & 127) * 4;
    f32x4 r0 = *(const f32x4*)(Wk + (size_t)(d0 + 0) * 512 + m0);
    f32x4 r1 = *(const f32x4*)(Wk + (size_t)(d0 + 1) * 512 + m0);
    f32x4 r2 = *(const f32x4*)(Wk + (size_t)(d0 + 2) * 512 + m0);
    f32x4 r3 = *(const f32x4*)(Wk + (size_t)(d0 + 3) * 512 + m0);
#pragma unroll
    for (int j = 0; j < 4; ++j) {
      bf16x4 o;
      o[0] = (__bf16)r0[j]; o[1] = (__bf16)r1[j];
      o[2] = (__bf16)r2[j]; o[3] = (__bf16)r3[j];
      *(bf16x4*)(WkT + (size_t)(m0 + j) * 256 + d0) = o;
    }
  } else {
    const int t2 = idx - 106496;                // Wv [256 d][512 m] -> WvT f32
    const int d0 = (t2 >> 7) * 4, m0 = (t2 & 127) * 4;
    f32x4 r0 = *(const f32x4*)(Wv + (size_t)(d0 + 0) * 512 + m0);
    f32x4 r1 = *(const f32x4*)(Wv + (size_t)(d0 + 1) * 512 + m0);
    f32x4 r2 = *(const f32x4*)(Wv + (size_t)(d0 + 2) * 512 + m0);
    f32x4 r3 = *(const f32x4*)(Wv + (size_t)(d0 + 3) * 512 + m0);
#pragma unroll
    for (int j = 0; j < 4; ++j) {
      f32x4 o;
      o[0] = r0[j]; o[1] = r1[j]; o[2] = r2[j]; o[3] = r3[j];
      *(f32x4*)(WvT + (size_t)(m0 + j) * 256 + d0) = o;
    }
  }
}

// =====================================================================
// qproj: Qw[bk][d] = T@Wq^T (verbatim proven m97 path, grid 8)
// =====================================================================
__global__ __launch_bounds__(256) void qproj(const __bf16* __restrict__ Wqb,
                                             const __bf16* __restrict__ Tbf,
                                             __bf16* __restrict__ Qw) {
  __shared__ __align__(16) __bf16 At[4096];
  __shared__ __align__(16) __bf16 Bt[4096];
  const int tid = threadIdx.x, lane = tid & 63;
  const int q = lane >> 4, ln = lane & 15;
  const int w = tid >> 6, wm = w >> 1, wn = w & 1;
  const int t = blockIdx.x;
  const int nbase = (t & 3) * 128;   // T rows (bk)
  const int mbase = (t >> 2) * 128;  // Wq rows (d)
  f32x4 acc[4][4] = {};
  for (int kt = 0; kt < 16; ++kt) {
    const int k0 = kt * 32;
    __syncthreads();
#pragma unroll
    for (int s = 0; s < 2; ++s) {
      const int cbase = (tid & 192) + s * 256;
      const int cc = cbase + lane;
      const int row = cc >> 2, kc = (cc & 3) * 8;
      cp16(&At[cbase * 8], Wqb + (size_t)(mbase + row) * 512 + k0 + kc);
      cp16(&Bt[cbase * 8], Tbf + (size_t)(nbase + row) * 512 + k0 + kc);
    }
    __syncthreads();
    bf16x8 af[4], bfr[4];
#pragma unroll
    for (int f = 0; f < 4; ++f) {
      af[f]  = *(const bf16x8*)&At[(wm * 64 + f * 16 + ln) * 32 + q * 8];
      bfr[f] = *(const bf16x8*)&Bt[(wn * 64 + f * 16 + ln) * 32 + q * 8];
    }
#pragma unroll
    for (int fm = 0; fm < 4; ++fm)
#pragma unroll
      for (int fn = 0; fn < 4; ++fn)
        acc[fm][fn] = MFMA(af[fm], bfr[fn], acc[fm][fn], 0, 0, 0);
  }
#pragma unroll
  for (int fm = 0; fm < 4; ++fm)
#pragma unroll
    for (int fn = 0; fn < 4; ++fn) {
      const int m = mbase + wm * 64 + fm * 16 + q * 4;
      const int n = nbase + wn * 64 + fn * 16 + ln;
      f32x4 v = acc[fm][fn];
      bf16x4 o;
      o[0] = (__bf16)v[0]; o[1] = (__bf16)v[1];
      o[2] = (__bf16)v[2]; o[3] = (__bf16)v[3];
      *(bf16x4*)&Qw[(size_t)n * 256 + m] = o;
    }
}

// =====================================================================
// qwk: QWkb[bk][m'] = Qw @ Wk = sum_d Qw[bk][d]*WkT[m'][d], K=256, grid 16
// =====================================================================
__global__ __launch_bounds__(256) void qwk(const __bf16* __restrict__ WkT,
                                           const __bf16* __restrict__ Qwp,
                                           __bf16* __restrict__ QWkb) {
  __shared__ __align__(16) __bf16 At[4096];
  __shared__ __align__(16) __bf16 Bt[4096];
  const int tid = threadIdx.x, lane = tid & 63;
  const int q = lane >> 4, ln = lane & 15;
  const int w = tid >> 6, wm = w >> 1, wn = w & 1;
  const int t = blockIdx.x;
  const int nbase = (t & 3) * 128;   // Qw rows (bk)
  const int mbase = (t >> 2) * 128;  // WkT rows (m')
  f32x4 acc[4][4] = {};
  for (int kt = 0; kt < 8; ++kt) {
    const int k0 = kt * 32;
    __syncthreads();
#pragma unroll
    for (int s = 0; s < 2; ++s) {
      const int cbase = (tid & 192) + s * 256;
      const int cc = cbase + lane;
      const int row = cc >> 2, kc = (cc & 3) * 8;
      cp16(&At[cbase * 8], WkT + (size_t)(mbase + row) * 256 + k0 + kc);
      cp16(&Bt[cbase * 8], Qwp + (size_t)(nbase + row) * 256 + k0 + kc);
    }
    __syncthreads();
    bf16x8 af[4], bfr[4];
#pragma unroll
    for (int f = 0; f < 4; ++f) {
      af[f]  = *(const bf16x8*)&At[(wm * 64 + f * 16 + ln) * 32 + q * 8];
      bfr[f] = *(const bf16x8*)&Bt[(wn * 64 + f * 16 + ln) * 32 + q * 8];
    }
#pragma unroll
    for (int fm = 0; fm < 4; ++fm)
#pragma unroll
      for (int fn = 0; fn < 4; ++fn)
        acc[fm][fn] = MFMA(af[fm], bfr[fn], acc[fm][fn], 0, 0, 0);
  }
#pragma unroll
  for (int fm = 0; fm < 4; ++fm)
#pragma unroll
    for (int fn = 0; fn < 4; ++fn) {
      const int m = mbase + wm * 64 + fm * 16 + q * 4;
      const int n = nbase + wn * 64 + fn * 16 + ln;
      f32x4 v = acc[fm][fn];
      bf16x4 o;
      o[0] = (__bf16)v[0]; o[1] = (__bf16)v[1];
      o[2] = (__bf16)v[2]; o[3] = (__bf16)v[3];
      *(bf16x4*)&QWkb[(size_t)n * 512 + m] = o;
    }
}

// =====================================================================
// fused_main: per block (c=chunk of 256 n, b): stream E once.
// Per 64-n subtile: GEMM1 S=QWk@E^T -> P=exp(S/16+logP) -> GEMM2 F+=P@E.
// E staged to LDS in both row layout (Er, pad 520) and transposed layout
// (EtT, pad 72 + 16B-unit XOR swizzle on write/read -> <=2 lanes/bank).
// 512 thr / 8 waves; QWk A-frags in registers; 3 raw barriers/subtile.
// =====================================================================
__device__ __forceinline__ void load_e(f32x4 (&ev)[16], const float* Eb,
                                       int s, int rg, int cg0) {
#pragma unroll
  for (int i = 0; i < 4; ++i) {
    const int cg = cg0 + i * 32;
#pragma unroll
    for (int r = 0; r < 4; ++r)
      ev[i * 4 + r] = *(const f32x4*)(Eb + (size_t)(s * 64 + rg * 4 + r) * 512 + cg * 4);
  }
}
__device__ __forceinline__ void cvtwrite_e(const f32x4 (&ev)[16], __bf16* Er,
                                           __bf16* EtT, int rg, int cg0) {
#pragma unroll
  for (int i = 0; i < 4; ++i) {
    const int cg = cg0 + i * 32;
#pragma unroll
    for (int r = 0; r < 4; ++r) {
      bf16x4 rw;
      rw[0] = (__bf16)ev[i*4+r][0]; rw[1] = (__bf16)ev[i*4+r][1];
      rw[2] = (__bf16)ev[i*4+r][2]; rw[3] = (__bf16)ev[i*4+r][3];
      *(bf16x4*)((char*)Er + (size_t)(rg * 4 + r) * 1040 + cg * 8) = rw;
    }
#pragma unroll
    for (int j = 0; j < 4; ++j) {
      bf16x4 tw;
      tw[0] = (__bf16)ev[i*4+0][j]; tw[1] = (__bf16)ev[i*4+1][j];
      tw[2] = (__bf16)ev[i*4+2][j]; tw[3] = (__bf16)ev[i*4+3][j];
      const int m = cg * 4 + j;
      const int u = (rg >> 1) ^ ((m >> 3) & 7);          // 16B-unit swizzle
      *(bf16x4*)((char*)EtT + (size_t)m * 144 + u * 16 + (rg & 1) * 8) = tw;
    }
  }
}

__global__ __launch_bounds__(512, 2) void fused_main(
    const float* __restrict__ E, const __bf16* __restrict__ QWkb,
    const float* __restrict__ Pb, __bf16* __restrict__ Pws,
    float* __restrict__ Fpart, float* __restrict__ rowsum) {
  __shared__ __align__(16) __bf16 Er[64 * 520];     // 66560 B
  __shared__ __align__(16) __bf16 EtT[512 * 72];    // 73728 B
  __shared__ __align__(16) __bf16 Plds[32 * 72];    //  4608 B
  __shared__ __align__(16) float Lp[256];
  __shared__ float rsum[32];

  const int tid = threadIdx.x;
  const int lane = tid & 63;
  const int q = lane >> 4, ln = lane & 15;
  const int w = tid >> 6;         // 0..7
  const int kf = w >> 2;          // GEMM1 k-frag (0..1)
  const int nf = w & 3;           // GEMM1 n-frag (0..3)
  const int b = blockIdx.y, c = blockIdx.x;
  const int rg = tid >> 5;        // 0..15
  const int cg0 = tid & 31;

  const float* Eb = E + ((size_t)b * 4096 + (size_t)c * 256) * 512;

  // QWk A-fragments -> registers (64 VGPR, reused all subtiles)
  bf16x8 qf[16];
  {
    const __bf16* qr = QWkb + (size_t)(b * 32 + kf * 16 + ln) * 512 + q * 8;
#pragma unroll
    for (int kk = 0; kk < 16; ++kk) qf[kk] = *(const bf16x8*)(qr + kk * 32);
  }
  if (tid < 256) {
    float p = Pb[b * 4096 + c * 256 + tid];
    Lp[tid] = __logf(fminf(fmaxf(p, 0.1f), 0.9f));
  }
  if (tid < 32) rsum[tid] = 0.f;

  f32x4 ev[16];
  load_e(ev, Eb, 0, rg, cg0);
  VMCNT0;
  cvtwrite_e(ev, Er, EtT, rg, cg0);
  load_e(ev, Eb, 1, rg, cg0);
  LGKM0; BARRAW();

  f32x4 facc[2][4] = {};
  for (int s = 0; s < 4; ++s) {
    // ---- phase1: GEMM1 (S = QWk @ E^T) + P ----
    f32x4 sacc = {0.f, 0.f, 0.f, 0.f};
#pragma unroll
    for (int kk = 0; kk < 16; ++kk) {
      bf16x8 bb = *(const bf16x8*)((char*)Er + (size_t)(nf * 16 + ln) * 1040 + kk * 64 + q * 16);
      sacc = MFMA(qf[kk], bb, sacc, 0, 0, 0);
    }
    const float lp = Lp[s * 64 + nf * 16 + ln];
    float pv[4];
#pragma unroll
    for (int r = 0; r < 4; ++r) {
      pv[r] = __expf(sacc[r] * 0.0625f + lp);
      Plds[(kf * 16 + q * 4 + r) * 72 + nf * 16 + ln] = (__bf16)pv[r];
    }
#pragma unroll
    for (int mm = 1; mm < 16; mm <<= 1)
#pragma unroll
      for (int r = 0; r < 4; ++r) pv[r] += __shfl_xor(pv[r], mm, 64);
    if (ln == 0) {
#pragma unroll
      for (int r = 0; r < 4; ++r) atomicAdd(&rsum[kf * 16 + q * 4 + r], pv[r]);
    }
    LGKM0; BARRAW();
    // ---- phase2a: GEMM2 (F += P @ E) + Pws copy ----
#pragma unroll
    for (int kkn = 0; kkn < 2; ++kkn) {
      bf16x8 pa0 = *(const bf16x8*)((char*)Plds + (size_t)(ln) * 144 + kkn * 64 + q * 16);
      bf16x8 pa1 = *(const bf16x8*)((char*)Plds + (size_t)(16 + ln) * 144 + kkn * 64 + q * 16);
#pragma unroll
      for (int mf = 0; mf < 4; ++mf) {
        const int m = w * 64 + mf * 16 + ln;
        const int u = (kkn * 4 + q) ^ ((m >> 3) & 7);
        bf16x8 vb = *(const bf16x8*)((char*)EtT + (size_t)m * 144 + u * 16);
        facc[0][mf] = MFMA(pa0, vb, facc[0][mf], 0, 0, 0);
        facc[1][mf] = MFMA(pa1, vb, facc[1][mf], 0, 0, 0);
      }
    }
    {
      const int k = tid >> 4, j = (tid & 15) * 4;
      bf16x4 pc = *(const bf16x4*)((char*)Plds + (size_t)k * 144 + j * 2);
      *(bf16x4*)(Pws + (size_t)(b * 32 + k) * 4096 + c * 256 + s * 64 + j) = pc;
    }
    BARRAW();
    // ---- phase2b: stage next subtile ----
    if (s < 3) {
      VMCNT0;
      cvtwrite_e(ev, Er, EtT, rg, cg0);
      if (s < 2) load_e(ev, Eb, s + 2, rg, cg0);
      LGKM0; BARRAW();
    }
  }
  // ---- epilogue: partial F plane + rowsum atomics ----
  float* Fp = Fpart + ((size_t)c * 512 + b * 32) * 512;
#pragma unroll
  for (int kf2 = 0; kf2 < 2; ++kf2)
#pragma unroll
    for (int mf = 0; mf < 4; ++mf)
#pragma unroll
      for (int r = 0; r < 4; ++r)
        Fp[(size_t)(kf2 * 16 + q * 4 + r) * 512 + w * 64 + mf * 16 + ln] = facc[kf2][mf][r];
  if (tid < 32) atomicAdd(&rowsum[b * 32 + tid], rsum[tid]);
}

// =====================================================================
// norm_p: A(f32) = Pws(bf16) / rowsum[row]  (unchanged)
// =====================================================================
__global__ __launch_bounds__(256) void norm_p(const __bf16* __restrict__ Pws,
                                              const float* __restrict__ rowsum,
                                              float* __restrict__ Aout) {
  const size_t idx = ((size_t)blockIdx.x * 256 + threadIdx.x) * 4;
  const int row = (int)(idx >> 12);
  const float invs = 1.0f / rowsum[row];
  bf16x4 p = *(const bf16x4*)(Pws + idx);
  f32x4 o;
  o[0] = (float)p[0] * invs; o[1] = (float)p[1] * invs;
  o[2] = (float)p[2] * invs; o[3] = (float)p[3] * invs;
  *(f32x4*)(Aout + idx) = o;
}

// =====================================================================
// final: Fsum = sum_chunks Fpart; F_agg = Fsum@Wv^T (f32, via WvT);
// F2 = F_agg@Wo^T (f32); L2 normalize (rowsum cancels).
// =====================================================================
__global__ __launch_bounds__(256) void final_kernel(const float* __restrict__ Fpart,
                                                    const float* __restrict__ WvT,
                                                    const float* __restrict__ Wo,
                                                    float* __restrict__ Fout) {
  __shared__ float fl[512];
  __shared__ float agg[256];
  __shared__ float redbuf[4];
  const int row = blockIdx.x;
  const int t = threadIdx.x;
  float s0 = 0.f, s1 = 0.f;
#pragma unroll
  for (int cc = 0; cc < 16; ++cc) {
    const float* p = Fpart + (size_t)cc * 262144 + (size_t)row * 512;
    s0 += p[t]; s1 += p[t + 256];
  }
  fl[t] = s0; fl[t + 256] = s1;
  __syncthreads();
  float a0 = 0.f, a1 = 0.f, a2 = 0.f, a3 = 0.f;
  for (int m = 0; m < 512; m += 4) {
    a0 += fl[m]     * WvT[(size_t)m * 256 + t];
    a1 += fl[m + 1] * WvT[(size_t)(m + 1) * 256 + t];
    a2 += fl[m + 2] * WvT[(size_t)(m + 2) * 256 + t];
    a3 += fl[m + 3] * WvT[(size_t)(m + 3) * 256 + t];
  }
  agg[t] = (a0 + a1) + (a2 + a3);
  __syncthreads();
  float f2[2];
#pragma unroll
  for (int h = 0; h < 2; ++h) {
    const float* wr = Wo + (size_t)(t + h * 256) * 256;
    float d0 = 0.f, d1 = 0.f, d2 = 0.f, d3 = 0.f;
    for (int d = 0; d < 256; d += 4) {
      f32x4 wv = *(const f32x4*)(wr + d);
      d0 += wv[0] * agg[d];     d1 += wv[1] * agg[d + 1];
      d2 += wv[2] * agg[d + 2]; d3 += wv[3] * agg[d + 3];
    }
    f2[h] = (d0 + d1) + (d2 + d3);
  }
  float ps = f2[0] * f2[0] + f2[1] * f2[1];
#pragma unroll
  for (int m = 1; m < 64; m <<= 1) ps += __shfl_xor(ps, m, 64);
  if ((t & 63) == 0) redbuf[t >> 6] = ps;
  __syncthreads();
  const float tot = redbuf[0] + redbuf[1] + redbuf[2] + redbuf[3];
  const float sc = 1.0f / (sqrtf(tot) + 1e-8f);
  Fout[(size_t)row * 512 + t] = f2[0] * sc;
  Fout[(size_t)row * 512 + t + 256] = f2[1] * sc;
}

// =====================================================================
extern "C" void kernel_launch(void* const* d_in, const int* in_sizes, int n_in,
                              void* d_out, int out_size, void* d_ws, size_t ws_size,
                              hipStream_t stream) {
  const float* E  = (const float*)d_in[0];  // [16,4096,512]
  const float* T  = (const float*)d_in[1];  // [16,32,512]
  const float* Pb = (const float*)d_in[2];  // [16,4096]
  const float* Wq = (const float*)d_in[3];  // [256,512]
  const float* Wk = (const float*)d_in[4];
  const float* Wv = (const float*)d_in[5];
  const float* Wo = (const float*)d_in[6];  // [512,256]

  float* out  = (float*)d_out;
  float* Fout = out;             // [512][512] f32
  float* Aout = out + 262144;    // [512][4096] f32

  char* ws = (char*)d_ws;
  float*  Fpart = (float*)ws;                    // [16][512][512] f32  16777216 B
  __bf16* Pws   = (__bf16*)(ws + 16777216);      // [512][4096] bf16     4194304 B
  __bf16* Tbf   = (__bf16*)(ws + 20971520);      //                       524288 B
  __bf16* Wqb   = (__bf16*)(ws + 21495808);      //                       262144 B
  __bf16* WkT   = (__bf16*)(ws + 21757952);      // [512][256] bf16       262144 B
  float*  WvT   = (float*)(ws + 22020096);       // [512][256] f32        524288 B
  __bf16* Qw    = (__bf16*)(ws + 22544384);      // [512][256] bf16       262144 B
  __bf16* QWkb  = (__bf16*)(ws + 22806528);      // [512][512] bf16       524288 B
  float*  rowsum = (float*)(ws + 23330816);      // [512] f32

  hipMemsetAsync(rowsum, 0, 2048, stream);

  cvt_small<<<448, 256, 0, stream>>>(Wq, Wk, Wv, T, Wqb, Tbf, WkT, WvT);
  qproj<<<8, 256, 0, stream>>>(Wqb, Tbf, Qw);
  qwk<<<16, 256, 0, stream>>>(WkT, Qw, QWkb);
  fused_main<<<dim3(16, 16), 512, 0, stream>>>(E, QWkb, Pb, Pws, Fpart, rowsum);
  norm_p<<<2048, 256, 0, stream>>>(Pws, rowsum, Aout);
  final_kernel<<<512, 256, 0, stream>>>(Fpart, WvT, Wo, Fout);
}